// Round 10
// baseline (316.262 us; speedup 1.0000x reference)
//
#include <hip/hip_runtime.h>

#define N_NODES 50000
#define BN_EPS 1e-5f
#define NBUCK 391
#define NCHUNK 1000
#define ENTCAP 5120

using short8 = __attribute__((ext_vector_type(8))) short;
using f32x4  = __attribute__((ext_vector_type(4))) float;

__device__ __forceinline__ float b2f(ushort h) { return __uint_as_float(((uint)h) << 16); }
__device__ __forceinline__ float blo(uint v) { return __uint_as_float(v << 16); }
__device__ __forceinline__ float bhi(uint v) { return __uint_as_float(v & 0xffff0000u); }
__device__ __forceinline__ ushort f2b(float f) {
    uint u = __float_as_uint(f);
    u += 0x7FFF + ((u >> 16) & 1);   // round-to-nearest-even
    return (ushort)(u >> 16);
}
__device__ __forceinline__ uint packb(float lo, float hi) {
    return ((uint)f2b(hi) << 16) | (uint)f2b(lo);
}
__device__ __forceinline__ int xcd_chunk(int bid) {
    return (bid & 7) * (NCHUNK / 8) + (bid >> 3);
}

// ================= setup mega-kernel: hist | convert_x | convert_w | zero =================
#define B_CX 6250   // M*32/256
#define B_CW 192    // 3*16384/256
#define B_Z  8      // 2048 floats of statsrep
__global__ __launch_bounds__(256) void setup_kernel(const int* __restrict__ dst, int nE, int chunk,
                                                    int* __restrict__ histT,
                                                    const float4* __restrict__ x4,
                                                    ushort4* __restrict__ xb,
                                                    const float* __restrict__ w11,
                                                    const float* __restrict__ w12,
                                                    const float* __restrict__ w21,
                                                    ushort* __restrict__ o11,
                                                    ushort* __restrict__ o12,
                                                    ushort* __restrict__ o21,
                                                    float* __restrict__ statsrep) {
    __shared__ int h[NBUCK];
    const int b = blockIdx.x;
    const int tid = threadIdx.x;
    if (b < NCHUNK) {
        for (int i = tid; i < NBUCK; i += 256) h[i] = 0;
        __syncthreads();
        const int c = xcd_chunk(b);
        const int lo = c * chunk, hi = min(lo + chunk, nE);
        for (int i = lo + tid; i < hi; i += 256) atomicAdd(&h[dst[i] >> 7], 1);
        __syncthreads();
        for (int k = tid; k < NBUCK; k += 256) histT[k * NCHUNK + c] = h[k];
    } else if (b < NCHUNK + B_CX) {
        int i = (b - NCHUNK) * 256 + tid;
        float4 v = x4[i];
        ushort4 o;
        o.x = f2b(v.x); o.y = f2b(v.y); o.z = f2b(v.z); o.w = f2b(v.w);
        xb[i] = o;
    } else if (b < NCHUNK + B_CX + B_CW) {
        int id = (b - NCHUNK - B_CX) * 256 + tid;     // 0..49151
        int m = id >> 14;
        int within = id & 16383;
        int k = within >> 7, n = within & 127;
        const float* W = (m == 0) ? w11 : (m == 1) ? w12 : w21;
        ushort* O = (m == 0) ? o11 : (m == 1) ? o12 : o21;
        O[n * 128 + k] = f2b(W[within]);
    } else {
        int i = (b - NCHUNK - B_CX - B_CW) * 256 + tid;
        if (i < 2048) statsrep[i] = 0.f;
    }
}

// ================= radix: per-bucket totals =================
__global__ __launch_bounds__(256) void tot_kernel(const int* __restrict__ histT,
                                                  int* __restrict__ tot) {
    __shared__ int s[256];
    int acc = 0;
    for (int i = threadIdx.x; i < NCHUNK; i += 256) acc += histT[blockIdx.x * NCHUNK + i];
    s[threadIdx.x] = acc;
    __syncthreads();
    for (int d = 128; d > 0; d >>= 1) {
        if (threadIdx.x < d) s[threadIdx.x] += s[threadIdx.x + d];
        __syncthreads();
    }
    if (threadIdx.x == 0) tot[blockIdx.x] = s[0];
}

// ================= radix: per-bucket base + per-chunk exclusive offsets =================
__global__ __launch_bounds__(1024) void base_scan_kernel(const int* __restrict__ tot,
                                                         const int* __restrict__ histT,
                                                         int* __restrict__ base_bc,
                                                         int* __restrict__ bucketbase,
                                                         int* __restrict__ rowptr, int nE) {
    __shared__ int s[1024];
    const int b = blockIdx.x;
    const int t = threadIdx.x;
    int acc = 0;
    for (int i = t; i < b; i += 1024) acc += tot[i];
    s[t] = acc;
    __syncthreads();
    for (int d = 512; d > 0; d >>= 1) {
        if (t < d) s[t] += s[t + d];
        __syncthreads();
    }
    const int bbase = s[0];
    __syncthreads();
    int v = (t < NCHUNK) ? histT[b * NCHUNK + t] : 0;
    s[t] = v;
    __syncthreads();
    for (int d = 1; d < 1024; d <<= 1) {
        int u = (t >= d) ? s[t - d] : 0;
        __syncthreads();
        s[t] += u;
        __syncthreads();
    }
    if (t < NCHUNK) base_bc[b * NCHUNK + t] = bbase + s[t] - v;  // exclusive
    if (t == 0) {
        bucketbase[b] = bbase;
        if (b == NBUCK - 1) bucketbase[NBUCK] = bbase + tot[b];
        if (b == 0) rowptr[N_NODES] = nE;
    }
}

// ================= radix pass 2: placement =================
__global__ __launch_bounds__(256) void place_kernel(const int* __restrict__ src,
                                                    const int* __restrict__ dst, int nE,
                                                    int chunk,
                                                    const int* __restrict__ base_bc,
                                                    uint* __restrict__ bdata) {
    __shared__ int off[NBUCK];
    const int c = xcd_chunk(blockIdx.x);
    for (int i = threadIdx.x; i < NBUCK; i += 256) off[i] = base_bc[i * NCHUNK + c];
    __syncthreads();
    const int lo = c * chunk, hi = min(lo + chunk, nE);
    for (int i = lo + threadIdx.x; i < hi; i += 256) {
        int s = src[i], d = dst[i];
        int pos = atomicAdd(&off[d >> 7], 1);
        bdata[pos] = ((uint)(d & 127) << 16) | (uint)s;
    }
}

// ================= per-bucket LDS counting sort -> rowptr + perm =================
__global__ __launch_bounds__(256) void csr_build_kernel(const int* __restrict__ bucketbase,
                                                        const uint* __restrict__ bdata,
                                                        int* __restrict__ rowptr,
                                                        ushort* __restrict__ perm, int M) {
    __shared__ uint ent[ENTCAP];
    __shared__ int hist[128];
    __shared__ int scn[128];
    __shared__ int cur[128];
    const int b = blockIdx.x;
    const int tid = threadIdx.x;
    const int bb = bucketbase[b];
    const int nb = min(bucketbase[b + 1] - bb, ENTCAP);
    if (tid < 128) hist[tid] = 0;
    for (int i = tid; i < nb; i += 256) ent[i] = bdata[bb + i];
    __syncthreads();
    for (int i = tid; i < nb; i += 256) atomicAdd(&hist[ent[i] >> 16], 1);
    __syncthreads();
    if (tid < 128) scn[tid] = hist[tid];
    __syncthreads();
    for (int d = 1; d < 128; d <<= 1) {
        int v = 0;
        if (tid < 128 && tid >= d) v = scn[tid - d];
        __syncthreads();
        if (tid < 128) scn[tid] += v;
        __syncthreads();
    }
    if (tid < 128) {
        int ex = scn[tid] - hist[tid];
        cur[tid] = ex;
        int node = b * 128 + tid;
        if (node < M) rowptr[node] = bb + ex;
    }
    __syncthreads();
    for (int i = tid; i < nb; i += 256) {
        uint e = ent[i];
        int lp = atomicAdd(&cur[e >> 16], 1);
        perm[bb + lp] = (ushort)(e & 0xffffu);
    }
}

// ================= gather v3: feature-chunked (4 chunks x 32 feats), XCD-L2-resident ======
// grid = nodegroup*4; chunk = blockIdx&3 -> XCD k handles chunk k&3 only (3.2MB slice, L2-fit)
// wave: 8 edge slots x 8 lanes x uint2 (4 features/lane)
template<bool BN>
__global__ __launch_bounds__(256) void gather_kernel(const uint2* __restrict__ xb,
                                                     const int* __restrict__ rowptr,
                                                     const ushort* __restrict__ perm,
                                                     const float* __restrict__ statsrep,
                                                     const float* __restrict__ gma,
                                                     const float* __restrict__ bta,
                                                     float invM,
                                                     uint2* __restrict__ out, int M) {
    const int chunk = blockIdx.x & 3;
    const int grp   = blockIdx.x >> 2;
    __shared__ float scs[32], shs[32];
    if (BN) {
        if (threadIdx.x < 32) {
            int c = chunk * 32 + threadIdx.x;
            float s = 0.f, q = 0.f;
            #pragma unroll
            for (int rep = 0; rep < 8; ++rep) {
                s += statsrep[rep * 256 + c];
                q += statsrep[rep * 256 + 128 + c];
            }
            float mean = s * invM;
            float var = q * invM - mean * mean;
            float sc = rsqrtf(var + BN_EPS) * gma[c];
            scs[threadIdx.x] = sc;
            shs[threadIdx.x] = bta[c] - mean * sc;
        }
        __syncthreads();
    }
    const int node = grp * 4 + (threadIdx.x >> 6);
    if (node >= M) return;
    const int lane = threadIdx.x & 63;
    const int g = lane >> 3;            // edge slot 0..7
    const int r = lane & 7;             // uint2 within the 64B slice
    const int base = chunk * 8 + r;     // uint2 index within the 32-uint2 row
    float a0, a1, a2, a3;
    if (g == 0) {
        uint2 v = xb[node * 32 + base];
        a0 = blo(v.x); a1 = bhi(v.x); a2 = blo(v.y); a3 = bhi(v.y);
    } else {
        a0 = a1 = a2 = a3 = 0.f;
    }
    const int beg = rowptr[node], end = rowptr[node + 1];
    int e = beg + g;
    while (e + 8 < end) {
        int s0 = perm[e];
        int s1 = perm[e + 8];
        uint2 v0 = xb[s0 * 32 + base];
        uint2 v1 = xb[s1 * 32 + base];
        a0 += blo(v0.x); a1 += bhi(v0.x); a2 += blo(v0.y); a3 += bhi(v0.y);
        a0 += blo(v1.x); a1 += bhi(v1.x); a2 += blo(v1.y); a3 += bhi(v1.y);
        e += 16;
    }
    if (e < end) {
        uint2 v0 = xb[(int)perm[e] * 32 + base];
        a0 += blo(v0.x); a1 += bhi(v0.x); a2 += blo(v0.y); a3 += bhi(v0.y);
    }
    // reduce across the 8 edge slots
    a0 += __shfl_xor(a0, 8); a0 += __shfl_xor(a0, 16); a0 += __shfl_xor(a0, 32);
    a1 += __shfl_xor(a1, 8); a1 += __shfl_xor(a1, 16); a1 += __shfl_xor(a1, 32);
    a2 += __shfl_xor(a2, 8); a2 += __shfl_xor(a2, 16); a2 += __shfl_xor(a2, 32);
    a3 += __shfl_xor(a3, 8); a3 += __shfl_xor(a3, 16); a3 += __shfl_xor(a3, 32);
    if (g == 0) {
        if (BN) {
            const int f0 = r * 4;
            const float deg1 = (float)(end - beg + 1);
            a0 = a0 * scs[f0 + 0] + deg1 * shs[f0 + 0];
            a1 = a1 * scs[f0 + 1] + deg1 * shs[f0 + 1];
            a2 = a2 * scs[f0 + 2] + deg1 * shs[f0 + 2];
            a3 = a3 * scs[f0 + 3] + deg1 * shs[f0 + 3];
        }
        out[node * 32 + base] = make_uint2(packb(a0, a1), packb(a2, a3));
    }
}

// ================= MFMA matmul: C[M x 128] = relu(A @ W + b), bf16 in/out, no LDS =========
__global__ __launch_bounds__(256) void mfma_mm_kernel(const ushort* __restrict__ A,
                                                      const ushort* __restrict__ Wt, // Wt[n][k]
                                                      const float* __restrict__ b,
                                                      ushort* __restrict__ C, int M) {
    const int wid = threadIdx.x >> 6;
    const int lane = threadIdx.x & 63;
    const int row0 = blockIdx.x * 64 + wid * 16;
    const int r = lane & 15;
    const int kg = lane >> 4;

    const int arow = min(row0 + r, M - 1);
    const ushort* Arow = A + (size_t)arow * 128 + kg * 8;
    short8 a[4];
    #pragma unroll
    for (int kb = 0; kb < 4; ++kb)
        a[kb] = *(const short8*)(Arow + kb * 32);

    #pragma unroll
    for (int c = 0; c < 8; ++c) {
        f32x4 acc = {0.f, 0.f, 0.f, 0.f};
        const ushort* Wcol = Wt + (size_t)(c * 16 + r) * 128 + kg * 8;
        #pragma unroll
        for (int kb = 0; kb < 4; ++kb) {
            short8 bb = *(const short8*)(Wcol + kb * 32);
            acc = __builtin_amdgcn_mfma_f32_16x16x32_bf16(a[kb], bb, acc, 0, 0, 0);
        }
        float bias = b[c * 16 + r];
        #pragma unroll
        for (int j = 0; j < 4; ++j) {
            int orow = row0 + kg * 4 + j;
            if (orow < M) {
                float v = fmaxf(acc[j] + bias, 0.f);
                C[(size_t)orow * 128 + c * 16 + r] = f2b(v);
            }
        }
    }
}

// ================= MFMA matmul + BN-stats epilogue (for layer-1 second GEMM) ==============
__global__ __launch_bounds__(256) void mfma_mm_stats_kernel(const ushort* __restrict__ A,
                                                            const ushort* __restrict__ Wt,
                                                            const float* __restrict__ b,
                                                            ushort* __restrict__ C,
                                                            float* __restrict__ statsrep, int M) {
    const int wid = threadIdx.x >> 6;
    const int lane = threadIdx.x & 63;
    const int row0 = blockIdx.x * 64 + wid * 16;
    const int r = lane & 15;
    const int kg = lane >> 4;

    const int arow = min(row0 + r, M - 1);
    const ushort* Arow = A + (size_t)arow * 128 + kg * 8;
    short8 a[4];
    #pragma unroll
    for (int kb = 0; kb < 4; ++kb)
        a[kb] = *(const short8*)(Arow + kb * 32);

    float* sr = statsrep + (blockIdx.x & 7) * 256;
    #pragma unroll
    for (int c = 0; c < 8; ++c) {
        f32x4 acc = {0.f, 0.f, 0.f, 0.f};
        const ushort* Wcol = Wt + (size_t)(c * 16 + r) * 128 + kg * 8;
        #pragma unroll
        for (int kb = 0; kb < 4; ++kb) {
            short8 bb = *(const short8*)(Wcol + kb * 32);
            acc = __builtin_amdgcn_mfma_f32_16x16x32_bf16(a[kb], bb, acc, 0, 0, 0);
        }
        const float bias = b[c * 16 + r];
        float s = 0.f, q = 0.f;
        #pragma unroll
        for (int j = 0; j < 4; ++j) {
            int orow = row0 + kg * 4 + j;
            float v = fmaxf(acc[j] + bias, 0.f);
            if (orow < M) C[(size_t)orow * 128 + c * 16 + r] = f2b(v);
            else v = 0.f;
            s += v; q += v * v;
        }
        s += __shfl_xor(s, 16); s += __shfl_xor(s, 32);
        q += __shfl_xor(q, 16); q += __shfl_xor(q, 32);
        if (kg == 0) {
            atomicAdd(&sr[c * 16 + r], s);
            atomicAdd(&sr[128 + c * 16 + r], q);
        }
    }
}

// ================= fused layer-2 tail: relu(A@W21+b21)@W22+b22 -> relu -> h2 + pblk ======
__global__ __launch_bounds__(256) void mm2_fused_kernel(const ushort* __restrict__ A,
                                                        const ushort* __restrict__ Wt,
                                                        const float* __restrict__ b1,
                                                        const float* __restrict__ W22,
                                                        const float* __restrict__ b22,
                                                        float* __restrict__ h2,
                                                        float4* __restrict__ pblk, int M) {
    __shared__ float bred[4][4];
    const int wid = threadIdx.x >> 6;
    const int lane = threadIdx.x & 63;
    const int row0 = blockIdx.x * 64 + wid * 16;
    const int r = lane & 15;
    const int kg = lane >> 4;

    const int arow = min(row0 + r, M - 1);
    const ushort* Arow = A + (size_t)arow * 128 + kg * 8;
    short8 a[4];
    #pragma unroll
    for (int kb = 0; kb < 4; ++kb)
        a[kb] = *(const short8*)(Arow + kb * 32);

    float w2a[8], w2b[8];
    #pragma unroll
    for (int c = 0; c < 8; ++c) {
        w2a[c] = W22[(c * 16 + r) * 2 + 0];
        w2b[c] = W22[(c * 16 + r) * 2 + 1];
    }

    float s0[4] = {0.f, 0.f, 0.f, 0.f};
    float s1[4] = {0.f, 0.f, 0.f, 0.f};
    #pragma unroll
    for (int c = 0; c < 8; ++c) {
        f32x4 acc = {0.f, 0.f, 0.f, 0.f};
        const ushort* Wcol = Wt + (size_t)(c * 16 + r) * 128 + kg * 8;
        #pragma unroll
        for (int kb = 0; kb < 4; ++kb) {
            short8 bb = *(const short8*)(Wcol + kb * 32);
            acc = __builtin_amdgcn_mfma_f32_16x16x32_bf16(a[kb], bb, acc, 0, 0, 0);
        }
        float bias = b1[c * 16 + r];
        #pragma unroll
        for (int j = 0; j < 4; ++j) {
            int orow = row0 + kg * 4 + j;
            float v = fmaxf(acc[j] + bias, 0.f);
            if (orow >= M) v = 0.f;
            s0[j] += v * w2a[c];
            s1[j] += v * w2b[c];
        }
    }
    #pragma unroll
    for (int j = 0; j < 4; ++j) {
        #pragma unroll
        for (int d = 1; d < 16; d <<= 1) {
            s0[j] += __shfl_xor(s0[j], d);
            s1[j] += __shfl_xor(s1[j], d);
        }
    }
    float bs[4] = {0.f, 0.f, 0.f, 0.f};
    if (r == 0) {
        const float bb0 = b22[0], bb1 = b22[1];
        #pragma unroll
        for (int j = 0; j < 4; ++j) {
            int orow = row0 + kg * 4 + j;
            if (orow < M) {
                float o0 = fmaxf(s0[j] + bb0, 0.f);
                float o1 = fmaxf(s1[j] + bb1, 0.f);
                h2[(size_t)orow * 2 + 0] = o0;
                h2[(size_t)orow * 2 + 1] = o1;
                bs[0] += o0; bs[1] += o1; bs[2] += o0 * o0; bs[3] += o1 * o1;
            }
        }
    }
    #pragma unroll
    for (int k = 0; k < 4; ++k) {
        bs[k] += __shfl_xor(bs[k], 16);
        bs[k] += __shfl_xor(bs[k], 32);
    }
    if (lane == 0) {
        #pragma unroll
        for (int k = 0; k < 4; ++k) bred[wid][k] = bs[k];
    }
    __syncthreads();
    if (threadIdx.x == 0)
        pblk[blockIdx.x] = make_float4(bred[0][0] + bred[1][0] + bred[2][0] + bred[3][0],
                                       bred[0][1] + bred[1][1] + bred[2][1] + bred[3][1],
                                       bred[0][2] + bred[1][2] + bred[2][2] + bred[3][2],
                                       bred[0][3] + bred[1][3] + bred[2][3] + bred[3][3]);
}

// ================= final: reduce pblk -> BN2 scale/shift -> apply, f32 out =================
__global__ __launch_bounds__(256) void bn_apply2_kernel(const float* __restrict__ h,
                                                        const float4* __restrict__ pblk, int nblk,
                                                        const float* __restrict__ gma,
                                                        const float* __restrict__ bta,
                                                        float* __restrict__ y, int n4, float invM) {
    __shared__ float4 red[256];
    const int tid = threadIdx.x;
    float4 s = make_float4(0.f, 0.f, 0.f, 0.f);
    for (int b = tid; b < nblk; b += 256) {
        float4 t = pblk[b];
        s.x += t.x; s.y += t.y; s.z += t.z; s.w += t.w;
    }
    red[tid] = s;
    __syncthreads();
    for (int d = 128; d > 0; d >>= 1) {
        if (tid < d) {
            red[tid].x += red[tid + d].x;
            red[tid].y += red[tid + d].y;
            red[tid].z += red[tid + d].z;
            red[tid].w += red[tid + d].w;
        }
        __syncthreads();
    }
    const float4 tot = red[0];
    const float m0 = tot.x * invM, m1 = tot.y * invM;
    const float v0 = tot.z * invM - m0 * m0, v1 = tot.w * invM - m1 * m1;
    const float sc0 = rsqrtf(v0 + BN_EPS) * gma[0], sc1 = rsqrtf(v1 + BN_EPS) * gma[1];
    const float sh0 = bta[0] - m0 * sc0, sh1 = bta[1] - m1 * sc1;
    int gid = blockIdx.x * 256 + tid;
    if (gid >= n4) return;
    float4 v = ((const float4*)h)[gid];
    float4 o;
    o.x = v.x * sc0 + sh0;
    o.y = v.y * sc1 + sh1;
    o.z = v.z * sc0 + sh0;
    o.w = v.w * sc1 + sh1;
    ((float4*)y)[gid] = o;
}

extern "C" void kernel_launch(void* const* d_in, const int* in_sizes, int n_in,
                              void* d_out, int out_size, void* d_ws, size_t ws_size,
                              hipStream_t stream) {
    const float* x   = (const float*)d_in[0];
    const int*   ei  = (const int*)d_in[1];
    const float* w11 = (const float*)d_in[2];
    const float* b11 = (const float*)d_in[3];
    const float* w12 = (const float*)d_in[4];
    const float* b12 = (const float*)d_in[5];
    const float* g1  = (const float*)d_in[6];
    const float* be1 = (const float*)d_in[7];
    const float* w21 = (const float*)d_in[8];
    const float* b21 = (const float*)d_in[9];
    const float* w22 = (const float*)d_in[10];
    const float* b22 = (const float*)d_in[11];
    const float* g2  = (const float*)d_in[12];
    const float* be2 = (const float*)d_in[13];

    const int M  = N_NODES;
    const int nE = in_sizes[1] / 2;
    const int* src = ei;
    const int* dst = ei + nE;
    const int chunk = (nE + NCHUNK - 1) / NCHUNK;
    const int nblk = (M + 63) / 64;
    const int ngrp = (M + 3) / 4;

    const size_t RB = (size_t)50048 * 128 * 2;      // padded bf16 feature buffer bytes
    char* p = (char*)d_ws;
    ushort* xb   = (ushort*)p;  p += RB;
    ushort* gbuf = (ushort*)p;  p += RB;
    ushort* tbuf = (ushort*)p;  p += RB;
    ushort* hbuf = (ushort*)p;  p += RB;
    float*  h2   = (float*)p;   p += 400128;        // 50000*2 f32
    ushort* wt11 = (ushort*)p;  p += 32768;
    ushort* wt12 = (ushort*)p;  p += 32768;
    ushort* wt21 = (ushort*)p;  p += 32768;
    float* statsrep = (float*)p; p += 2048 * 4;     // 8 x (sum[128], sumsq[128])
    float4* pblk = (float4*)p;  p += (size_t)nblk * 16 + 64;
    int*  histT  = (int*)p;     p += (size_t)NBUCK * NCHUNK * 4;
    int*  base_bc= (int*)p;     p += (size_t)NBUCK * NCHUNK * 4;
    int*  tot    = (int*)p;     p += 512 * 4;
    int*  bktbase= (int*)p;     p += 512 * 4;
    int*  rowptr = (int*)p;     p += (size_t)(M + 8) * 4;
    ushort* perm = (ushort*)p;  p += (size_t)nE * 2 + 64;
    uint*  bdata = (uint*)p;

    const float invM = 1.0f / (float)M;

    // ---- setup: hist + convert_x + convert_w + zero (one dispatch) ----
    setup_kernel<<<NCHUNK + B_CX + B_CW + B_Z, 256, 0, stream>>>(
        dst, nE, chunk, histT, (const float4*)x, (ushort4*)xb,
        w11, w12, w21, wt11, wt12, wt21, statsrep);
    // ---- CSR build ----
    tot_kernel<<<NBUCK, 256, 0, stream>>>(histT, tot);
    base_scan_kernel<<<NBUCK, 1024, 0, stream>>>(tot, histT, base_bc, bktbase, rowptr, nE);
    place_kernel<<<NCHUNK, 256, 0, stream>>>(src, dst, nE, chunk, base_bc, bdata);
    csr_build_kernel<<<NBUCK, 256, 0, stream>>>(bktbase, bdata, rowptr, perm, M);

    // ---- layer 1 ----
    gather_kernel<false><<<ngrp * 4, 256, 0, stream>>>((const uint2*)xb, rowptr, perm,
                                                       nullptr, nullptr, nullptr, 0.f,
                                                       (uint2*)gbuf, M);
    mfma_mm_kernel<<<nblk, 256, 0, stream>>>(gbuf, wt11, b11, tbuf, M);
    mfma_mm_stats_kernel<<<nblk, 256, 0, stream>>>(tbuf, wt12, b12, hbuf, statsrep, M);

    // ---- layer 2 (BN1 finalize+fold fused into gather; 128->2 projection fused into GEMM) ----
    gather_kernel<true><<<ngrp * 4, 256, 0, stream>>>((const uint2*)hbuf, rowptr, perm,
                                                      statsrep, g1, be1, invM,
                                                      (uint2*)gbuf, M);
    mm2_fused_kernel<<<nblk, 256, 0, stream>>>(gbuf, wt21, b21, w22, b22, h2, pblk, M);
    bn_apply2_kernel<<<(M / 2 + 255) / 256, 256, 0, stream>>>(h2, pblk, nblk, g2, be2,
                                                              (float*)d_out, M / 2, invM);
}

// Round 11
// 227.789 us; speedup vs baseline: 1.3884x; 1.3884x over previous
//
#include <hip/hip_runtime.h>

#define N_NODES 50000
#define BN_EPS 1e-5f
#define NBUCK 391
#define NCHUNK 1000
#define ENTCAP 5120

using short8 = __attribute__((ext_vector_type(8))) short;
using f32x4  = __attribute__((ext_vector_type(4))) float;

__device__ __forceinline__ float b2f(ushort h) { return __uint_as_float(((uint)h) << 16); }
__device__ __forceinline__ float blo(uint v) { return __uint_as_float(v << 16); }
__device__ __forceinline__ float bhi(uint v) { return __uint_as_float(v & 0xffff0000u); }
__device__ __forceinline__ ushort f2b(float f) {
    uint u = __float_as_uint(f);
    u += 0x7FFF + ((u >> 16) & 1);   // round-to-nearest-even
    return (ushort)(u >> 16);
}
__device__ __forceinline__ uint packb(float lo, float hi) {
    return ((uint)f2b(hi) << 16) | (uint)f2b(lo);
}
__device__ __forceinline__ int xcd_chunk(int bid) {
    return (bid & 7) * (NCHUNK / 8) + (bid >> 3);
}

// ================= setup mega-kernel: hist | convert_x | convert_w | zero =================
#define B_CX 6250   // M*32/256
#define B_CW 192    // 3*16384/256
#define B_Z  8      // 2048 floats of statsrep
__global__ __launch_bounds__(256) void setup_kernel(const int* __restrict__ dst, int nE, int chunk,
                                                    int* __restrict__ histT,
                                                    const float4* __restrict__ x4,
                                                    ushort4* __restrict__ xb,
                                                    const float* __restrict__ w11,
                                                    const float* __restrict__ w12,
                                                    const float* __restrict__ w21,
                                                    ushort* __restrict__ o11,
                                                    ushort* __restrict__ o12,
                                                    ushort* __restrict__ o21,
                                                    float* __restrict__ statsrep) {
    __shared__ int h[NBUCK];
    const int b = blockIdx.x;
    const int tid = threadIdx.x;
    if (b < NCHUNK) {
        for (int i = tid; i < NBUCK; i += 256) h[i] = 0;
        __syncthreads();
        const int c = xcd_chunk(b);
        const int lo = c * chunk, hi = min(lo + chunk, nE);
        for (int i = lo + tid; i < hi; i += 256) atomicAdd(&h[dst[i] >> 7], 1);
        __syncthreads();
        for (int k = tid; k < NBUCK; k += 256) histT[k * NCHUNK + c] = h[k];
    } else if (b < NCHUNK + B_CX) {
        int i = (b - NCHUNK) * 256 + tid;
        float4 v = x4[i];
        ushort4 o;
        o.x = f2b(v.x); o.y = f2b(v.y); o.z = f2b(v.z); o.w = f2b(v.w);
        xb[i] = o;
    } else if (b < NCHUNK + B_CX + B_CW) {
        int id = (b - NCHUNK - B_CX) * 256 + tid;     // 0..49151
        int m = id >> 14;
        int within = id & 16383;
        int k = within >> 7, n = within & 127;
        const float* W = (m == 0) ? w11 : (m == 1) ? w12 : w21;
        ushort* O = (m == 0) ? o11 : (m == 1) ? o12 : o21;
        O[n * 128 + k] = f2b(W[within]);
    } else {
        int i = (b - NCHUNK - B_CX - B_CW) * 256 + tid;
        if (i < 2048) statsrep[i] = 0.f;
    }
}

// ================= radix: per-bucket totals =================
__global__ __launch_bounds__(256) void tot_kernel(const int* __restrict__ histT,
                                                  int* __restrict__ tot) {
    __shared__ int s[256];
    int acc = 0;
    for (int i = threadIdx.x; i < NCHUNK; i += 256) acc += histT[blockIdx.x * NCHUNK + i];
    s[threadIdx.x] = acc;
    __syncthreads();
    for (int d = 128; d > 0; d >>= 1) {
        if (threadIdx.x < d) s[threadIdx.x] += s[threadIdx.x + d];
        __syncthreads();
    }
    if (threadIdx.x == 0) tot[blockIdx.x] = s[0];
}

// ================= radix: per-bucket base + per-chunk exclusive offsets =================
__global__ __launch_bounds__(1024) void base_scan_kernel(const int* __restrict__ tot,
                                                         const int* __restrict__ histT,
                                                         int* __restrict__ base_bc,
                                                         int* __restrict__ bucketbase,
                                                         int* __restrict__ rowptr, int nE) {
    __shared__ int s[1024];
    const int b = blockIdx.x;
    const int t = threadIdx.x;
    int acc = 0;
    for (int i = t; i < b; i += 1024) acc += tot[i];
    s[t] = acc;
    __syncthreads();
    for (int d = 512; d > 0; d >>= 1) {
        if (t < d) s[t] += s[t + d];
        __syncthreads();
    }
    const int bbase = s[0];
    __syncthreads();
    int v = (t < NCHUNK) ? histT[b * NCHUNK + t] : 0;
    s[t] = v;
    __syncthreads();
    for (int d = 1; d < 1024; d <<= 1) {
        int u = (t >= d) ? s[t - d] : 0;
        __syncthreads();
        s[t] += u;
        __syncthreads();
    }
    if (t < NCHUNK) base_bc[b * NCHUNK + t] = bbase + s[t] - v;  // exclusive
    if (t == 0) {
        bucketbase[b] = bbase;
        if (b == NBUCK - 1) bucketbase[NBUCK] = bbase + tot[b];
        if (b == 0) rowptr[N_NODES] = nE;
    }
}

// ================= radix pass 2: placement =================
__global__ __launch_bounds__(256) void place_kernel(const int* __restrict__ src,
                                                    const int* __restrict__ dst, int nE,
                                                    int chunk,
                                                    const int* __restrict__ base_bc,
                                                    uint* __restrict__ bdata) {
    __shared__ int off[NBUCK];
    const int c = xcd_chunk(blockIdx.x);
    for (int i = threadIdx.x; i < NBUCK; i += 256) off[i] = base_bc[i * NCHUNK + c];
    __syncthreads();
    const int lo = c * chunk, hi = min(lo + chunk, nE);
    for (int i = lo + threadIdx.x; i < hi; i += 256) {
        int s = src[i], d = dst[i];
        int pos = atomicAdd(&off[d >> 7], 1);
        bdata[pos] = ((uint)(d & 127) << 16) | (uint)s;
    }
}

// ================= per-bucket LDS counting sort -> rowptr + perm =================
__global__ __launch_bounds__(256) void csr_build_kernel(const int* __restrict__ bucketbase,
                                                        const uint* __restrict__ bdata,
                                                        int* __restrict__ rowptr,
                                                        ushort* __restrict__ perm, int M) {
    __shared__ uint ent[ENTCAP];
    __shared__ int hist[128];
    __shared__ int scn[128];
    __shared__ int cur[128];
    const int b = blockIdx.x;
    const int tid = threadIdx.x;
    const int bb = bucketbase[b];
    const int nb = min(bucketbase[b + 1] - bb, ENTCAP);
    if (tid < 128) hist[tid] = 0;
    for (int i = tid; i < nb; i += 256) ent[i] = bdata[bb + i];
    __syncthreads();
    for (int i = tid; i < nb; i += 256) atomicAdd(&hist[ent[i] >> 16], 1);
    __syncthreads();
    if (tid < 128) scn[tid] = hist[tid];
    __syncthreads();
    for (int d = 1; d < 128; d <<= 1) {
        int v = 0;
        if (tid < 128 && tid >= d) v = scn[tid - d];
        __syncthreads();
        if (tid < 128) scn[tid] += v;
        __syncthreads();
    }
    if (tid < 128) {
        int ex = scn[tid] - hist[tid];
        cur[tid] = ex;
        int node = b * 128 + tid;
        if (node < M) rowptr[node] = bb + ex;
    }
    __syncthreads();
    for (int i = tid; i < nb; i += 256) {
        uint e = ent[i];
        int lp = atomicAdd(&cur[e >> 16], 1);
        perm[bb + lp] = (ushort)(e & 0xffffu);
    }
}

// ================= gather (16 lanes/edge, 8-deep), optional fused BN finalize+apply ======
#define ACC4(v) { acc[0] += blo(v.x); acc[1] += bhi(v.x); \
                  acc[2] += blo(v.y); acc[3] += bhi(v.y); \
                  acc[4] += blo(v.z); acc[5] += bhi(v.z); \
                  acc[6] += blo(v.w); acc[7] += bhi(v.w); }

template<bool BN>
__global__ __launch_bounds__(256) void gather_kernel(const uint4* __restrict__ xb,
                                                     const int* __restrict__ rowptr,
                                                     const ushort* __restrict__ perm,
                                                     const float* __restrict__ statsrep,
                                                     const float* __restrict__ gma,
                                                     const float* __restrict__ bta,
                                                     float invM,
                                                     uint4* __restrict__ out, int M) {
    __shared__ float scs[128], shs[128];
    if (BN) {
        if (threadIdx.x < 128) {
            int c = threadIdx.x;
            float s = 0.f, q = 0.f;
            #pragma unroll
            for (int rep = 0; rep < 8; ++rep) {
                s += statsrep[rep * 256 + c];
                q += statsrep[rep * 256 + 128 + c];
            }
            float mean = s * invM;
            float var = q * invM - mean * mean;
            float sc = rsqrtf(var + BN_EPS) * gma[c];
            scs[c] = sc;
            shs[c] = bta[c] - mean * sc;
        }
        __syncthreads();
    }
    const int node = blockIdx.x * 4 + (threadIdx.x >> 6);
    if (node >= M) return;
    const int lane = threadIdx.x & 63;
    const int g4 = lane >> 4;       // edge slot 0..3
    const int r = lane & 15;        // 16B chunk (features r*8 .. r*8+7)
    float acc[8];
    if (g4 == 0) {
        uint4 v = xb[node * 16 + r];
        acc[0] = blo(v.x); acc[1] = bhi(v.x);
        acc[2] = blo(v.y); acc[3] = bhi(v.y);
        acc[4] = blo(v.z); acc[5] = bhi(v.z);
        acc[6] = blo(v.w); acc[7] = bhi(v.w);
    } else {
        #pragma unroll
        for (int k = 0; k < 8; ++k) acc[k] = 0.f;
    }
    const int beg = rowptr[node], end = rowptr[node + 1];
    int e = beg + g4;
    // 8-deep: this group's edges e, e+4, ..., e+28
    while (e + 28 < end) {
        int s0 = perm[e],      s1 = perm[e + 4],  s2 = perm[e + 8],  s3 = perm[e + 12];
        int s4 = perm[e + 16], s5 = perm[e + 20], s6 = perm[e + 24], s7 = perm[e + 28];
        uint4 v0 = xb[s0 * 16 + r];
        uint4 v1 = xb[s1 * 16 + r];
        uint4 v2 = xb[s2 * 16 + r];
        uint4 v3 = xb[s3 * 16 + r];
        uint4 v4 = xb[s4 * 16 + r];
        uint4 v5 = xb[s5 * 16 + r];
        uint4 v6 = xb[s6 * 16 + r];
        uint4 v7 = xb[s7 * 16 + r];
        ACC4(v0); ACC4(v1); ACC4(v2); ACC4(v3);
        ACC4(v4); ACC4(v5); ACC4(v6); ACC4(v7);
        e += 32;
    }
    while (e + 4 < end) {
        int s0 = perm[e], s1 = perm[e + 4];
        uint4 v0 = xb[s0 * 16 + r];
        uint4 v1 = xb[s1 * 16 + r];
        ACC4(v0); ACC4(v1);
        e += 8;
    }
    if (e < end) {
        uint4 v0 = xb[(int)perm[e] * 16 + r];
        ACC4(v0);
    }
    #pragma unroll
    for (int k = 0; k < 8; ++k) {
        acc[k] += __shfl_xor(acc[k], 16);
        acc[k] += __shfl_xor(acc[k], 32);
    }
    if (g4 == 0) {
        if (BN) {
            const int f0 = r * 8;
            const float deg1 = (float)(end - beg + 1);
            #pragma unroll
            for (int k = 0; k < 8; ++k)
                acc[k] = acc[k] * scs[f0 + k] + deg1 * shs[f0 + k];
        }
        uint4 o;
        o.x = packb(acc[0], acc[1]);
        o.y = packb(acc[2], acc[3]);
        o.z = packb(acc[4], acc[5]);
        o.w = packb(acc[6], acc[7]);
        out[node * 16 + r] = o;
    }
}

// ================= MFMA matmul: C[M x 128] = relu(A @ W + b), bf16 in/out, no LDS =========
__global__ __launch_bounds__(256) void mfma_mm_kernel(const ushort* __restrict__ A,
                                                      const ushort* __restrict__ Wt, // Wt[n][k]
                                                      const float* __restrict__ b,
                                                      ushort* __restrict__ C, int M) {
    const int wid = threadIdx.x >> 6;
    const int lane = threadIdx.x & 63;
    const int row0 = blockIdx.x * 64 + wid * 16;
    const int r = lane & 15;
    const int kg = lane >> 4;

    const int arow = min(row0 + r, M - 1);
    const ushort* Arow = A + (size_t)arow * 128 + kg * 8;
    short8 a[4];
    #pragma unroll
    for (int kb = 0; kb < 4; ++kb)
        a[kb] = *(const short8*)(Arow + kb * 32);

    #pragma unroll
    for (int c = 0; c < 8; ++c) {
        f32x4 acc = {0.f, 0.f, 0.f, 0.f};
        const ushort* Wcol = Wt + (size_t)(c * 16 + r) * 128 + kg * 8;
        #pragma unroll
        for (int kb = 0; kb < 4; ++kb) {
            short8 bb = *(const short8*)(Wcol + kb * 32);
            acc = __builtin_amdgcn_mfma_f32_16x16x32_bf16(a[kb], bb, acc, 0, 0, 0);
        }
        float bias = b[c * 16 + r];
        #pragma unroll
        for (int j = 0; j < 4; ++j) {
            int orow = row0 + kg * 4 + j;
            if (orow < M) {
                float v = fmaxf(acc[j] + bias, 0.f);
                C[(size_t)orow * 128 + c * 16 + r] = f2b(v);
            }
        }
    }
}

// ================= MFMA matmul + BN-stats epilogue (for layer-1 second GEMM) ==============
__global__ __launch_bounds__(256) void mfma_mm_stats_kernel(const ushort* __restrict__ A,
                                                            const ushort* __restrict__ Wt,
                                                            const float* __restrict__ b,
                                                            ushort* __restrict__ C,
                                                            float* __restrict__ statsrep, int M) {
    const int wid = threadIdx.x >> 6;
    const int lane = threadIdx.x & 63;
    const int row0 = blockIdx.x * 64 + wid * 16;
    const int r = lane & 15;
    const int kg = lane >> 4;

    const int arow = min(row0 + r, M - 1);
    const ushort* Arow = A + (size_t)arow * 128 + kg * 8;
    short8 a[4];
    #pragma unroll
    for (int kb = 0; kb < 4; ++kb)
        a[kb] = *(const short8*)(Arow + kb * 32);

    float* sr = statsrep + (blockIdx.x & 7) * 256;
    #pragma unroll
    for (int c = 0; c < 8; ++c) {
        f32x4 acc = {0.f, 0.f, 0.f, 0.f};
        const ushort* Wcol = Wt + (size_t)(c * 16 + r) * 128 + kg * 8;
        #pragma unroll
        for (int kb = 0; kb < 4; ++kb) {
            short8 bb = *(const short8*)(Wcol + kb * 32);
            acc = __builtin_amdgcn_mfma_f32_16x16x32_bf16(a[kb], bb, acc, 0, 0, 0);
        }
        const float bias = b[c * 16 + r];
        float s = 0.f, q = 0.f;
        #pragma unroll
        for (int j = 0; j < 4; ++j) {
            int orow = row0 + kg * 4 + j;
            float v = fmaxf(acc[j] + bias, 0.f);
            if (orow < M) C[(size_t)orow * 128 + c * 16 + r] = f2b(v);
            else v = 0.f;
            s += v; q += v * v;
        }
        s += __shfl_xor(s, 16); s += __shfl_xor(s, 32);
        q += __shfl_xor(q, 16); q += __shfl_xor(q, 32);
        if (kg == 0) {
            atomicAdd(&sr[c * 16 + r], s);
            atomicAdd(&sr[128 + c * 16 + r], q);
        }
    }
}

// ================= fused layer-2 tail: relu(A@W21+b21)@W22+b22 -> relu -> h2 + pblk ======
__global__ __launch_bounds__(256) void mm2_fused_kernel(const ushort* __restrict__ A,
                                                        const ushort* __restrict__ Wt,
                                                        const float* __restrict__ b1,
                                                        const float* __restrict__ W22,
                                                        const float* __restrict__ b22,
                                                        float* __restrict__ h2,
                                                        float4* __restrict__ pblk, int M) {
    __shared__ float bred[4][4];
    const int wid = threadIdx.x >> 6;
    const int lane = threadIdx.x & 63;
    const int row0 = blockIdx.x * 64 + wid * 16;
    const int r = lane & 15;
    const int kg = lane >> 4;

    const int arow = min(row0 + r, M - 1);
    const ushort* Arow = A + (size_t)arow * 128 + kg * 8;
    short8 a[4];
    #pragma unroll
    for (int kb = 0; kb < 4; ++kb)
        a[kb] = *(const short8*)(Arow + kb * 32);

    float w2a[8], w2b[8];
    #pragma unroll
    for (int c = 0; c < 8; ++c) {
        w2a[c] = W22[(c * 16 + r) * 2 + 0];
        w2b[c] = W22[(c * 16 + r) * 2 + 1];
    }

    float s0[4] = {0.f, 0.f, 0.f, 0.f};
    float s1[4] = {0.f, 0.f, 0.f, 0.f};
    #pragma unroll
    for (int c = 0; c < 8; ++c) {
        f32x4 acc = {0.f, 0.f, 0.f, 0.f};
        const ushort* Wcol = Wt + (size_t)(c * 16 + r) * 128 + kg * 8;
        #pragma unroll
        for (int kb = 0; kb < 4; ++kb) {
            short8 bb = *(const short8*)(Wcol + kb * 32);
            acc = __builtin_amdgcn_mfma_f32_16x16x32_bf16(a[kb], bb, acc, 0, 0, 0);
        }
        float bias = b1[c * 16 + r];
        #pragma unroll
        for (int j = 0; j < 4; ++j) {
            int orow = row0 + kg * 4 + j;
            float v = fmaxf(acc[j] + bias, 0.f);
            if (orow >= M) v = 0.f;
            s0[j] += v * w2a[c];
            s1[j] += v * w2b[c];
        }
    }
    #pragma unroll
    for (int j = 0; j < 4; ++j) {
        #pragma unroll
        for (int d = 1; d < 16; d <<= 1) {
            s0[j] += __shfl_xor(s0[j], d);
            s1[j] += __shfl_xor(s1[j], d);
        }
    }
    float bs[4] = {0.f, 0.f, 0.f, 0.f};
    if (r == 0) {
        const float bb0 = b22[0], bb1 = b22[1];
        #pragma unroll
        for (int j = 0; j < 4; ++j) {
            int orow = row0 + kg * 4 + j;
            if (orow < M) {
                float o0 = fmaxf(s0[j] + bb0, 0.f);
                float o1 = fmaxf(s1[j] + bb1, 0.f);
                h2[(size_t)orow * 2 + 0] = o0;
                h2[(size_t)orow * 2 + 1] = o1;
                bs[0] += o0; bs[1] += o1; bs[2] += o0 * o0; bs[3] += o1 * o1;
            }
        }
    }
    #pragma unroll
    for (int k = 0; k < 4; ++k) {
        bs[k] += __shfl_xor(bs[k], 16);
        bs[k] += __shfl_xor(bs[k], 32);
    }
    if (lane == 0) {
        #pragma unroll
        for (int k = 0; k < 4; ++k) bred[wid][k] = bs[k];
    }
    __syncthreads();
    if (threadIdx.x == 0)
        pblk[blockIdx.x] = make_float4(bred[0][0] + bred[1][0] + bred[2][0] + bred[3][0],
                                       bred[0][1] + bred[1][1] + bred[2][1] + bred[3][1],
                                       bred[0][2] + bred[1][2] + bred[2][2] + bred[3][2],
                                       bred[0][3] + bred[1][3] + bred[2][3] + bred[3][3]);
}

// ================= final: reduce pblk -> BN2 scale/shift -> apply, f32 out =================
__global__ __launch_bounds__(256) void bn_apply2_kernel(const float* __restrict__ h,
                                                        const float4* __restrict__ pblk, int nblk,
                                                        const float* __restrict__ gma,
                                                        const float* __restrict__ bta,
                                                        float* __restrict__ y, int n4, float invM) {
    __shared__ float4 red[256];
    const int tid = threadIdx.x;
    float4 s = make_float4(0.f, 0.f, 0.f, 0.f);
    for (int b = tid; b < nblk; b += 256) {
        float4 t = pblk[b];
        s.x += t.x; s.y += t.y; s.z += t.z; s.w += t.w;
    }
    red[tid] = s;
    __syncthreads();
    for (int d = 128; d > 0; d >>= 1) {
        if (tid < d) {
            red[tid].x += red[tid + d].x;
            red[tid].y += red[tid + d].y;
            red[tid].z += red[tid + d].z;
            red[tid].w += red[tid + d].w;
        }
        __syncthreads();
    }
    const float4 tot = red[0];
    const float m0 = tot.x * invM, m1 = tot.y * invM;
    const float v0 = tot.z * invM - m0 * m0, v1 = tot.w * invM - m1 * m1;
    const float sc0 = rsqrtf(v0 + BN_EPS) * gma[0], sc1 = rsqrtf(v1 + BN_EPS) * gma[1];
    const float sh0 = bta[0] - m0 * sc0, sh1 = bta[1] - m1 * sc1;
    int gid = blockIdx.x * 256 + tid;
    if (gid >= n4) return;
    float4 v = ((const float4*)h)[gid];
    float4 o;
    o.x = v.x * sc0 + sh0;
    o.y = v.y * sc1 + sh1;
    o.z = v.z * sc0 + sh0;
    o.w = v.w * sc1 + sh1;
    ((float4*)y)[gid] = o;
}

extern "C" void kernel_launch(void* const* d_in, const int* in_sizes, int n_in,
                              void* d_out, int out_size, void* d_ws, size_t ws_size,
                              hipStream_t stream) {
    const float* x   = (const float*)d_in[0];
    const int*   ei  = (const int*)d_in[1];
    const float* w11 = (const float*)d_in[2];
    const float* b11 = (const float*)d_in[3];
    const float* w12 = (const float*)d_in[4];
    const float* b12 = (const float*)d_in[5];
    const float* g1  = (const float*)d_in[6];
    const float* be1 = (const float*)d_in[7];
    const float* w21 = (const float*)d_in[8];
    const float* b21 = (const float*)d_in[9];
    const float* w22 = (const float*)d_in[10];
    const float* b22 = (const float*)d_in[11];
    const float* g2  = (const float*)d_in[12];
    const float* be2 = (const float*)d_in[13];

    const int M  = N_NODES;
    const int nE = in_sizes[1] / 2;
    const int* src = ei;
    const int* dst = ei + nE;
    const int chunk = (nE + NCHUNK - 1) / NCHUNK;
    const int nblk = (M + 63) / 64;

    const size_t RB = (size_t)50048 * 128 * 2;      // padded bf16 feature buffer bytes
    char* p = (char*)d_ws;
    ushort* xb   = (ushort*)p;  p += RB;
    ushort* gbuf = (ushort*)p;  p += RB;
    ushort* tbuf = (ushort*)p;  p += RB;
    ushort* hbuf = (ushort*)p;  p += RB;
    float*  h2   = (float*)p;   p += 400128;        // 50000*2 f32
    ushort* wt11 = (ushort*)p;  p += 32768;
    ushort* wt12 = (ushort*)p;  p += 32768;
    ushort* wt21 = (ushort*)p;  p += 32768;
    float* statsrep = (float*)p; p += 2048 * 4;     // 8 x (sum[128], sumsq[128])
    float4* pblk = (float4*)p;  p += (size_t)nblk * 16 + 64;
    int*  histT  = (int*)p;     p += (size_t)NBUCK * NCHUNK * 4;
    int*  base_bc= (int*)p;     p += (size_t)NBUCK * NCHUNK * 4;
    int*  tot    = (int*)p;     p += 512 * 4;
    int*  bktbase= (int*)p;     p += 512 * 4;
    int*  rowptr = (int*)p;     p += (size_t)(M + 8) * 4;
    ushort* perm = (ushort*)p;  p += (size_t)nE * 2 + 64;
    uint*  bdata = (uint*)p;

    const float invM = 1.0f / (float)M;

    // ---- setup: hist + convert_x + convert_w + zero (one dispatch) ----
    setup_kernel<<<NCHUNK + B_CX + B_CW + B_Z, 256, 0, stream>>>(
        dst, nE, chunk, histT, (const float4*)x, (ushort4*)xb,
        w11, w12, w21, wt11, wt12, wt21, statsrep);
    // ---- CSR build ----
    tot_kernel<<<NBUCK, 256, 0, stream>>>(histT, tot);
    base_scan_kernel<<<NBUCK, 1024, 0, stream>>>(tot, histT, base_bc, bktbase, rowptr, nE);
    place_kernel<<<NCHUNK, 256, 0, stream>>>(src, dst, nE, chunk, base_bc, bdata);
    csr_build_kernel<<<NBUCK, 256, 0, stream>>>(bktbase, bdata, rowptr, perm, M);

    // ---- layer 1 ----
    gather_kernel<false><<<(M + 3) / 4, 256, 0, stream>>>((const uint4*)xb, rowptr, perm,
                                                          nullptr, nullptr, nullptr, 0.f,
                                                          (uint4*)gbuf, M);
    mfma_mm_kernel<<<nblk, 256, 0, stream>>>(gbuf, wt11, b11, tbuf, M);
    mfma_mm_stats_kernel<<<nblk, 256, 0, stream>>>(tbuf, wt12, b12, hbuf, statsrep, M);

    // ---- layer 2 (BN1 finalize+fold fused into gather; 128->2 projection fused into GEMM) ----
    gather_kernel<true><<<(M + 3) / 4, 256, 0, stream>>>((const uint4*)hbuf, rowptr, perm,
                                                         statsrep, g1, be1, invM,
                                                         (uint4*)gbuf, M);
    mm2_fused_kernel<<<nblk, 256, 0, stream>>>(gbuf, wt21, b21, w22, b22, h2, pblk, M);
    bn_apply2_kernel<<<(M / 2 + 255) / 256, 256, 0, stream>>>(h2, pblk, nblk, g2, be2,
                                                              (float*)d_out, M / 2, invM);
}

// Round 12
// 204.275 us; speedup vs baseline: 1.5482x; 1.1151x over previous
//
#include <hip/hip_runtime.h>

#define N_NODES 50000
#define BN_EPS 1e-5f
#define NBUCK 391
#define NCHUNK 1000
#define ENTCAP 5120

using short4v = __attribute__((ext_vector_type(4))) short;
using short8 = __attribute__((ext_vector_type(8))) short;
using f32x4  = __attribute__((ext_vector_type(4))) float;

__device__ __forceinline__ float b2f(ushort h) { return __uint_as_float(((uint)h) << 16); }
__device__ __forceinline__ float blo(uint v) { return __uint_as_float(v << 16); }
__device__ __forceinline__ float bhi(uint v) { return __uint_as_float(v & 0xffff0000u); }
__device__ __forceinline__ ushort f2b(float f) {
    uint u = __float_as_uint(f);
    u += 0x7FFF + ((u >> 16) & 1);   // round-to-nearest-even
    return (ushort)(u >> 16);
}
__device__ __forceinline__ uint packb(float lo, float hi) {
    return ((uint)f2b(hi) << 16) | (uint)f2b(lo);
}
__device__ __forceinline__ int xcd_chunk(int bid) {
    return (bid & 7) * (NCHUNK / 8) + (bid >> 3);
}

// ================= setup mega-kernel: hist | convert_x | convert_w | zero =================
#define B_CX 6250   // M*32/256
#define B_CW 192    // 3*16384/256
#define B_Z  8      // 2048 floats of statsrep
__global__ __launch_bounds__(256) void setup_kernel(const int* __restrict__ dst, int nE, int chunk,
                                                    int* __restrict__ histT,
                                                    const float4* __restrict__ x4,
                                                    ushort4* __restrict__ xb,
                                                    const float* __restrict__ w11,
                                                    const float* __restrict__ w12,
                                                    const float* __restrict__ w21,
                                                    ushort* __restrict__ o11,
                                                    ushort* __restrict__ o12,
                                                    ushort* __restrict__ o21,
                                                    float* __restrict__ statsrep) {
    __shared__ int h[NBUCK];
    const int b = blockIdx.x;
    const int tid = threadIdx.x;
    if (b < NCHUNK) {
        for (int i = tid; i < NBUCK; i += 256) h[i] = 0;
        __syncthreads();
        const int c = xcd_chunk(b);
        const int lo = c * chunk, hi = min(lo + chunk, nE);
        for (int i = lo + tid; i < hi; i += 256) atomicAdd(&h[dst[i] >> 7], 1);
        __syncthreads();
        for (int k = tid; k < NBUCK; k += 256) histT[k * NCHUNK + c] = h[k];
    } else if (b < NCHUNK + B_CX) {
        int i = (b - NCHUNK) * 256 + tid;
        float4 v = x4[i];
        ushort4 o;
        o.x = f2b(v.x); o.y = f2b(v.y); o.z = f2b(v.z); o.w = f2b(v.w);
        xb[i] = o;
    } else if (b < NCHUNK + B_CX + B_CW) {
        int id = (b - NCHUNK - B_CX) * 256 + tid;     // 0..49151
        int m = id >> 14;
        int within = id & 16383;
        int k = within >> 7, n = within & 127;
        const float* W = (m == 0) ? w11 : (m == 1) ? w12 : w21;
        ushort* O = (m == 0) ? o11 : (m == 1) ? o12 : o21;
        O[n * 128 + k] = f2b(W[within]);
    } else {
        int i = (b - NCHUNK - B_CX - B_CW) * 256 + tid;
        if (i < 2048) statsrep[i] = 0.f;
    }
}

// ================= radix: per-bucket totals =================
__global__ __launch_bounds__(256) void tot_kernel(const int* __restrict__ histT,
                                                  int* __restrict__ tot) {
    __shared__ int s[256];
    int acc = 0;
    for (int i = threadIdx.x; i < NCHUNK; i += 256) acc += histT[blockIdx.x * NCHUNK + i];
    s[threadIdx.x] = acc;
    __syncthreads();
    for (int d = 128; d > 0; d >>= 1) {
        if (threadIdx.x < d) s[threadIdx.x] += s[threadIdx.x + d];
        __syncthreads();
    }
    if (threadIdx.x == 0) tot[blockIdx.x] = s[0];
}

// ================= radix: per-bucket base + per-chunk exclusive offsets =================
__global__ __launch_bounds__(1024) void base_scan_kernel(const int* __restrict__ tot,
                                                         const int* __restrict__ histT,
                                                         int* __restrict__ base_bc,
                                                         int* __restrict__ bucketbase,
                                                         int* __restrict__ rowptr, int nE) {
    __shared__ int s[1024];
    const int b = blockIdx.x;
    const int t = threadIdx.x;
    int acc = 0;
    for (int i = t; i < b; i += 1024) acc += tot[i];
    s[t] = acc;
    __syncthreads();
    for (int d = 512; d > 0; d >>= 1) {
        if (t < d) s[t] += s[t + d];
        __syncthreads();
    }
    const int bbase = s[0];
    __syncthreads();
    int v = (t < NCHUNK) ? histT[b * NCHUNK + t] : 0;
    s[t] = v;
    __syncthreads();
    for (int d = 1; d < 1024; d <<= 1) {
        int u = (t >= d) ? s[t - d] : 0;
        __syncthreads();
        s[t] += u;
        __syncthreads();
    }
    if (t < NCHUNK) base_bc[b * NCHUNK + t] = bbase + s[t] - v;  // exclusive
    if (t == 0) {
        bucketbase[b] = bbase;
        if (b == NBUCK - 1) bucketbase[NBUCK] = bbase + tot[b];
        if (b == 0) rowptr[N_NODES] = nE;
    }
}

// ================= radix pass 2: placement =================
__global__ __launch_bounds__(256) void place_kernel(const int* __restrict__ src,
                                                    const int* __restrict__ dst, int nE,
                                                    int chunk,
                                                    const int* __restrict__ base_bc,
                                                    uint* __restrict__ bdata) {
    __shared__ int off[NBUCK];
    const int c = xcd_chunk(blockIdx.x);
    for (int i = threadIdx.x; i < NBUCK; i += 256) off[i] = base_bc[i * NCHUNK + c];
    __syncthreads();
    const int lo = c * chunk, hi = min(lo + chunk, nE);
    for (int i = lo + threadIdx.x; i < hi; i += 256) {
        int s = src[i], d = dst[i];
        int pos = atomicAdd(&off[d >> 7], 1);
        bdata[pos] = ((uint)(d & 127) << 16) | (uint)s;
    }
}

// ================= per-bucket LDS counting sort -> rowptr + perm =================
__global__ __launch_bounds__(256) void csr_build_kernel(const int* __restrict__ bucketbase,
                                                        const uint* __restrict__ bdata,
                                                        int* __restrict__ rowptr,
                                                        ushort* __restrict__ perm, int M) {
    __shared__ uint ent[ENTCAP];
    __shared__ int hist[128];
    __shared__ int scn[128];
    __shared__ int cur[128];
    const int b = blockIdx.x;
    const int tid = threadIdx.x;
    const int bb = bucketbase[b];
    const int nb = min(bucketbase[b + 1] - bb, ENTCAP);
    if (tid < 128) hist[tid] = 0;
    for (int i = tid; i < nb; i += 256) ent[i] = bdata[bb + i];
    __syncthreads();
    for (int i = tid; i < nb; i += 256) atomicAdd(&hist[ent[i] >> 16], 1);
    __syncthreads();
    if (tid < 128) scn[tid] = hist[tid];
    __syncthreads();
    for (int d = 1; d < 128; d <<= 1) {
        int v = 0;
        if (tid < 128 && tid >= d) v = scn[tid - d];
        __syncthreads();
        if (tid < 128) scn[tid] += v;
        __syncthreads();
    }
    if (tid < 128) {
        int ex = scn[tid] - hist[tid];
        cur[tid] = ex;
        int node = b * 128 + tid;
        if (node < M) rowptr[node] = bb + ex;
    }
    __syncthreads();
    for (int i = tid; i < nb; i += 256) {
        uint e = ent[i];
        int lp = atomicAdd(&cur[e >> 16], 1);
        perm[bb + lp] = (ushort)(e & 0xffffu);
    }
}

// ================= gather (16 lanes/edge, 4-deep), optional fused BN finalize+apply ======
#define ACC4(v) { acc[0] += blo(v.x); acc[1] += bhi(v.x); \
                  acc[2] += blo(v.y); acc[3] += bhi(v.y); \
                  acc[4] += blo(v.z); acc[5] += bhi(v.z); \
                  acc[6] += blo(v.w); acc[7] += bhi(v.w); }

template<bool BN>
__global__ __launch_bounds__(256) void gather_kernel(const uint4* __restrict__ xb,
                                                     const int* __restrict__ rowptr,
                                                     const ushort* __restrict__ perm,
                                                     const float* __restrict__ statsrep,
                                                     const float* __restrict__ gma,
                                                     const float* __restrict__ bta,
                                                     float invM,
                                                     uint4* __restrict__ out, int M) {
    __shared__ float scs[128], shs[128];
    if (BN) {
        if (threadIdx.x < 128) {
            int c = threadIdx.x;
            float s = 0.f, q = 0.f;
            #pragma unroll
            for (int rep = 0; rep < 8; ++rep) {
                s += statsrep[rep * 256 + c];
                q += statsrep[rep * 256 + 128 + c];
            }
            float mean = s * invM;
            float var = q * invM - mean * mean;
            float sc = rsqrtf(var + BN_EPS) * gma[c];
            scs[c] = sc;
            shs[c] = bta[c] - mean * sc;
        }
        __syncthreads();
    }
    const int node = blockIdx.x * 4 + (threadIdx.x >> 6);
    if (node >= M) return;
    const int lane = threadIdx.x & 63;
    const int g4 = lane >> 4;       // edge slot 0..3
    const int r = lane & 15;        // 16B chunk (features r*8 .. r*8+7)
    float acc[8];
    if (g4 == 0) {
        uint4 v = xb[node * 16 + r];
        acc[0] = blo(v.x); acc[1] = bhi(v.x);
        acc[2] = blo(v.y); acc[3] = bhi(v.y);
        acc[4] = blo(v.z); acc[5] = bhi(v.z);
        acc[6] = blo(v.w); acc[7] = bhi(v.w);
    } else {
        #pragma unroll
        for (int k = 0; k < 8; ++k) acc[k] = 0.f;
    }
    const int beg = rowptr[node], end = rowptr[node + 1];
    int e = beg + g4;
    while (e + 12 < end) {
        int s0 = perm[e], s1 = perm[e + 4], s2 = perm[e + 8], s3 = perm[e + 12];
        uint4 v0 = xb[s0 * 16 + r];
        uint4 v1 = xb[s1 * 16 + r];
        uint4 v2 = xb[s2 * 16 + r];
        uint4 v3 = xb[s3 * 16 + r];
        ACC4(v0); ACC4(v1); ACC4(v2); ACC4(v3);
        e += 16;
    }
    while (e + 4 < end) {
        int s0 = perm[e], s1 = perm[e + 4];
        uint4 v0 = xb[s0 * 16 + r];
        uint4 v1 = xb[s1 * 16 + r];
        ACC4(v0); ACC4(v1);
        e += 8;
    }
    if (e < end) {
        uint4 v0 = xb[(int)perm[e] * 16 + r];
        ACC4(v0);
    }
    #pragma unroll
    for (int k = 0; k < 8; ++k) {
        acc[k] += __shfl_xor(acc[k], 16);
        acc[k] += __shfl_xor(acc[k], 32);
    }
    if (g4 == 0) {
        if (BN) {
            const int f0 = r * 8;
            const float deg1 = (float)(end - beg + 1);
            #pragma unroll
            for (int k = 0; k < 8; ++k)
                acc[k] = acc[k] * scs[f0 + k] + deg1 * shs[f0 + k];
        }
        uint4 o;
        o.x = packb(acc[0], acc[1]);
        o.y = packb(acc[2], acc[3]);
        o.z = packb(acc[4], acc[5]);
        o.w = packb(acc[6], acc[7]);
        out[node * 16 + r] = o;
    }
}

// ================= fused layer-1: relu(A@W11+b11)@W12+b12 -> relu -> C + stats ============
// v2: per-wave private bf16 LDS strip (no __syncthreads, 17.5KB), vector LDS reads.
__global__ __launch_bounds__(256) void mmL1_fused_kernel(const ushort* __restrict__ A,
                                                         const ushort* __restrict__ Wt1,
                                                         const float* __restrict__ b1,
                                                         const ushort* __restrict__ Wt2,
                                                         const float* __restrict__ b2,
                                                         ushort* __restrict__ C,
                                                         float* __restrict__ statsrep, int M) {
    __shared__ ushort T[4][16][140];   // per-wave [16 rows][128 cols + pad]
    const int wid = threadIdx.x >> 6;
    const int lane = threadIdx.x & 63;
    const int row0 = blockIdx.x * 64 + wid * 16;
    const int r = lane & 15;
    const int kg = lane >> 4;

    const int arow = min(row0 + r, M - 1);
    const ushort* Arow = A + (size_t)arow * 128 + kg * 8;
    short8 a[4];
    #pragma unroll
    for (int kb = 0; kb < 4; ++kb)
        a[kb] = *(const short8*)(Arow + kb * 32);

    // GEMM1 -> per-wave LDS strip (bf16, post-relu). Write mirrors the verified C-store
    // pattern: value (c,j) belongs at [row = kg*4+j][col = c*16+r].
    #pragma unroll
    for (int c = 0; c < 8; ++c) {
        f32x4 acc = {0.f, 0.f, 0.f, 0.f};
        const ushort* Wcol = Wt1 + (size_t)(c * 16 + r) * 128 + kg * 8;
        #pragma unroll
        for (int kb = 0; kb < 4; ++kb) {
            short8 bb = *(const short8*)(Wcol + kb * 32);
            acc = __builtin_amdgcn_mfma_f32_16x16x32_bf16(a[kb], bb, acc, 0, 0, 0);
        }
        const float bias = b1[c * 16 + r];
        #pragma unroll
        for (int j = 0; j < 4; ++j)
            T[wid][kg * 4 + j][c * 16 + r] = f2b(fmaxf(acc[j] + bias, 0.f));
    }
    // Same-wave LDS ops are processed in order: no barrier needed (private strip).

    // A2 fragments: read mirrors the verified A-load pattern: row r, cols kb*32+kg*8..+7.
    short8 a2[4];
    #pragma unroll
    for (int kb = 0; kb < 4; ++kb) {
        short4v lo = *(const short4v*)&T[wid][r][kb * 32 + kg * 8];
        short4v hi = *(const short4v*)&T[wid][r][kb * 32 + kg * 8 + 4];
        a2[kb][0] = lo[0]; a2[kb][1] = lo[1]; a2[kb][2] = lo[2]; a2[kb][3] = lo[3];
        a2[kb][4] = hi[0]; a2[kb][5] = hi[1]; a2[kb][6] = hi[2]; a2[kb][7] = hi[3];
    }

    // GEMM2 + epilogue (store + BN1 stats)
    float* sr = statsrep + (blockIdx.x & 7) * 256;
    #pragma unroll
    for (int c = 0; c < 8; ++c) {
        f32x4 acc = {0.f, 0.f, 0.f, 0.f};
        const ushort* Wcol = Wt2 + (size_t)(c * 16 + r) * 128 + kg * 8;
        #pragma unroll
        for (int kb = 0; kb < 4; ++kb) {
            short8 bb = *(const short8*)(Wcol + kb * 32);
            acc = __builtin_amdgcn_mfma_f32_16x16x32_bf16(a2[kb], bb, acc, 0, 0, 0);
        }
        const float bias = b2[c * 16 + r];
        float s = 0.f, q = 0.f;
        #pragma unroll
        for (int j = 0; j < 4; ++j) {
            int orow = row0 + kg * 4 + j;
            float v = fmaxf(acc[j] + bias, 0.f);
            if (orow < M) C[(size_t)orow * 128 + c * 16 + r] = f2b(v);
            else v = 0.f;
            s += v; q += v * v;
        }
        s += __shfl_xor(s, 16); s += __shfl_xor(s, 32);
        q += __shfl_xor(q, 16); q += __shfl_xor(q, 32);
        if (kg == 0) {
            atomicAdd(&sr[c * 16 + r], s);
            atomicAdd(&sr[128 + c * 16 + r], q);
        }
    }
}

// ================= fused layer-2 tail: relu(A@W21+b21)@W22+b22 -> relu -> h2 + pblk ======
__global__ __launch_bounds__(256) void mm2_fused_kernel(const ushort* __restrict__ A,
                                                        const ushort* __restrict__ Wt,
                                                        const float* __restrict__ b1,
                                                        const float* __restrict__ W22,
                                                        const float* __restrict__ b22,
                                                        float* __restrict__ h2,
                                                        float4* __restrict__ pblk, int M) {
    __shared__ float bred[4][4];
    const int wid = threadIdx.x >> 6;
    const int lane = threadIdx.x & 63;
    const int row0 = blockIdx.x * 64 + wid * 16;
    const int r = lane & 15;
    const int kg = lane >> 4;

    const int arow = min(row0 + r, M - 1);
    const ushort* Arow = A + (size_t)arow * 128 + kg * 8;
    short8 a[4];
    #pragma unroll
    for (int kb = 0; kb < 4; ++kb)
        a[kb] = *(const short8*)(Arow + kb * 32);

    float w2a[8], w2b[8];
    #pragma unroll
    for (int c = 0; c < 8; ++c) {
        w2a[c] = W22[(c * 16 + r) * 2 + 0];
        w2b[c] = W22[(c * 16 + r) * 2 + 1];
    }

    float s0[4] = {0.f, 0.f, 0.f, 0.f};
    float s1[4] = {0.f, 0.f, 0.f, 0.f};
    #pragma unroll
    for (int c = 0; c < 8; ++c) {
        f32x4 acc = {0.f, 0.f, 0.f, 0.f};
        const ushort* Wcol = Wt + (size_t)(c * 16 + r) * 128 + kg * 8;
        #pragma unroll
        for (int kb = 0; kb < 4; ++kb) {
            short8 bb = *(const short8*)(Wcol + kb * 32);
            acc = __builtin_amdgcn_mfma_f32_16x16x32_bf16(a[kb], bb, acc, 0, 0, 0);
        }
        float bias = b1[c * 16 + r];
        #pragma unroll
        for (int j = 0; j < 4; ++j) {
            int orow = row0 + kg * 4 + j;
            float v = fmaxf(acc[j] + bias, 0.f);
            if (orow >= M) v = 0.f;
            s0[j] += v * w2a[c];
            s1[j] += v * w2b[c];
        }
    }
    #pragma unroll
    for (int j = 0; j < 4; ++j) {
        #pragma unroll
        for (int d = 1; d < 16; d <<= 1) {
            s0[j] += __shfl_xor(s0[j], d);
            s1[j] += __shfl_xor(s1[j], d);
        }
    }
    float bs[4] = {0.f, 0.f, 0.f, 0.f};
    if (r == 0) {
        const float bb0 = b22[0], bb1 = b22[1];
        #pragma unroll
        for (int j = 0; j < 4; ++j) {
            int orow = row0 + kg * 4 + j;
            if (orow < M) {
                float o0 = fmaxf(s0[j] + bb0, 0.f);
                float o1 = fmaxf(s1[j] + bb1, 0.f);
                h2[(size_t)orow * 2 + 0] = o0;
                h2[(size_t)orow * 2 + 1] = o1;
                bs[0] += o0; bs[1] += o1; bs[2] += o0 * o0; bs[3] += o1 * o1;
            }
        }
    }
    #pragma unroll
    for (int k = 0; k < 4; ++k) {
        bs[k] += __shfl_xor(bs[k], 16);
        bs[k] += __shfl_xor(bs[k], 32);
    }
    if (lane == 0) {
        #pragma unroll
        for (int k = 0; k < 4; ++k) bred[wid][k] = bs[k];
    }
    __syncthreads();
    if (threadIdx.x == 0)
        pblk[blockIdx.x] = make_float4(bred[0][0] + bred[1][0] + bred[2][0] + bred[3][0],
                                       bred[0][1] + bred[1][1] + bred[2][1] + bred[3][1],
                                       bred[0][2] + bred[1][2] + bred[2][2] + bred[3][2],
                                       bred[0][3] + bred[1][3] + bred[2][3] + bred[3][3]);
}

// ================= final: reduce pblk -> BN2 scale/shift -> apply, f32 out =================
__global__ __launch_bounds__(256) void bn_apply2_kernel(const float* __restrict__ h,
                                                        const float4* __restrict__ pblk, int nblk,
                                                        const float* __restrict__ gma,
                                                        const float* __restrict__ bta,
                                                        float* __restrict__ y, int n4, float invM) {
    __shared__ float4 red[256];
    const int tid = threadIdx.x;
    float4 s = make_float4(0.f, 0.f, 0.f, 0.f);
    for (int b = tid; b < nblk; b += 256) {
        float4 t = pblk[b];
        s.x += t.x; s.y += t.y; s.z += t.z; s.w += t.w;
    }
    red[tid] = s;
    __syncthreads();
    for (int d = 128; d > 0; d >>= 1) {
        if (tid < d) {
            red[tid].x += red[tid + d].x;
            red[tid].y += red[tid + d].y;
            red[tid].z += red[tid + d].z;
            red[tid].w += red[tid + d].w;
        }
        __syncthreads();
    }
    const float4 tot = red[0];
    const float m0 = tot.x * invM, m1 = tot.y * invM;
    const float v0 = tot.z * invM - m0 * m0, v1 = tot.w * invM - m1 * m1;
    const float sc0 = rsqrtf(v0 + BN_EPS) * gma[0], sc1 = rsqrtf(v1 + BN_EPS) * gma[1];
    const float sh0 = bta[0] - m0 * sc0, sh1 = bta[1] - m1 * sc1;
    int gid = blockIdx.x * 256 + tid;
    if (gid >= n4) return;
    float4 v = ((const float4*)h)[gid];
    float4 o;
    o.x = v.x * sc0 + sh0;
    o.y = v.y * sc1 + sh1;
    o.z = v.z * sc0 + sh0;
    o.w = v.w * sc1 + sh1;
    ((float4*)y)[gid] = o;
}

extern "C" void kernel_launch(void* const* d_in, const int* in_sizes, int n_in,
                              void* d_out, int out_size, void* d_ws, size_t ws_size,
                              hipStream_t stream) {
    const float* x   = (const float*)d_in[0];
    const int*   ei  = (const int*)d_in[1];
    const float* w11 = (const float*)d_in[2];
    const float* b11 = (const float*)d_in[3];
    const float* w12 = (const float*)d_in[4];
    const float* b12 = (const float*)d_in[5];
    const float* g1  = (const float*)d_in[6];
    const float* be1 = (const float*)d_in[7];
    const float* w21 = (const float*)d_in[8];
    const float* b21 = (const float*)d_in[9];
    const float* w22 = (const float*)d_in[10];
    const float* b22 = (const float*)d_in[11];
    const float* g2  = (const float*)d_in[12];
    const float* be2 = (const float*)d_in[13];

    const int M  = N_NODES;
    const int nE = in_sizes[1] / 2;
    const int* src = ei;
    const int* dst = ei + nE;
    const int chunk = (nE + NCHUNK - 1) / NCHUNK;
    const int nblk = (M + 63) / 64;

    const size_t RB = (size_t)50048 * 128 * 2;      // padded bf16 feature buffer bytes
    char* p = (char*)d_ws;
    ushort* xb   = (ushort*)p;  p += RB;
    ushort* gbuf = (ushort*)p;  p += RB;
    ushort* tbuf = (ushort*)p;  p += RB;
    ushort* hbuf = (ushort*)p;  p += RB;
    float*  h2   = (float*)p;   p += 400128;        // 50000*2 f32
    ushort* wt11 = (ushort*)p;  p += 32768;
    ushort* wt12 = (ushort*)p;  p += 32768;
    ushort* wt21 = (ushort*)p;  p += 32768;
    float* statsrep = (float*)p; p += 2048 * 4;     // 8 x (sum[128], sumsq[128])
    float4* pblk = (float4*)p;  p += (size_t)nblk * 16 + 64;
    int*  histT  = (int*)p;     p += (size_t)NBUCK * NCHUNK * 4;
    int*  base_bc= (int*)p;     p += (size_t)NBUCK * NCHUNK * 4;
    int*  tot    = (int*)p;     p += 512 * 4;
    int*  bktbase= (int*)p;     p += 512 * 4;
    int*  rowptr = (int*)p;     p += (size_t)(M + 8) * 4;
    ushort* perm = (ushort*)p;  p += (size_t)nE * 2 + 64;
    uint*  bdata = (uint*)p;

    const float invM = 1.0f / (float)M;
    (void)tbuf;

    // ---- setup: hist + convert_x + convert_w + zero (one dispatch) ----
    setup_kernel<<<NCHUNK + B_CX + B_CW + B_Z, 256, 0, stream>>>(
        dst, nE, chunk, histT, (const float4*)x, (ushort4*)xb,
        w11, w12, w21, wt11, wt12, wt21, statsrep);
    // ---- CSR build ----
    tot_kernel<<<NBUCK, 256, 0, stream>>>(histT, tot);
    base_scan_kernel<<<NBUCK, 1024, 0, stream>>>(tot, histT, base_bc, bktbase, rowptr, nE);
    place_kernel<<<NCHUNK, 256, 0, stream>>>(src, dst, nE, chunk, base_bc, bdata);
    csr_build_kernel<<<NBUCK, 256, 0, stream>>>(bktbase, bdata, rowptr, perm, M);

    // ---- layer 1 (both GEMMs + BN1 stats fused, per-wave LDS transpose) ----
    gather_kernel<false><<<(M + 3) / 4, 256, 0, stream>>>((const uint4*)xb, rowptr, perm,
                                                          nullptr, nullptr, nullptr, 0.f,
                                                          (uint4*)gbuf, M);
    mmL1_fused_kernel<<<nblk, 256, 0, stream>>>(gbuf, wt11, b11, wt12, b12, hbuf, statsrep, M);

    // ---- layer 2 (BN1 finalize+fold fused into gather; 128->2 projection fused into GEMM) ----
    gather_kernel<true><<<(M + 3) / 4, 256, 0, stream>>>((const uint4*)hbuf, rowptr, perm,
                                                         statsrep, g1, be1, invM,
                                                         (uint4*)gbuf, M);
    mm2_fused_kernel<<<nblk, 256, 0, stream>>>(gbuf, wt21, b21, w22, b22, h2, pblk, M);
    bn_apply2_kernel<<<(M / 2 + 255) / 256, 256, 0, stream>>>(h2, pblk, nblk, g2, be2,
                                                              (float*)d_out, M / 2, invM);
}

// Round 13
// 201.060 us; speedup vs baseline: 1.5730x; 1.0160x over previous
//
#include <hip/hip_runtime.h>

#define N_NODES 50000
#define BN_EPS 1e-5f
#define NBUCK 391
#define NCHUNK 512
#define ENTCAP 5120

using short4v = __attribute__((ext_vector_type(4))) short;
using short8 = __attribute__((ext_vector_type(8))) short;
using f32x4  = __attribute__((ext_vector_type(4))) float;

__device__ __forceinline__ float b2f(ushort h) { return __uint_as_float(((uint)h) << 16); }
__device__ __forceinline__ float blo(uint v) { return __uint_as_float(v << 16); }
__device__ __forceinline__ float bhi(uint v) { return __uint_as_float(v & 0xffff0000u); }
__device__ __forceinline__ ushort f2b(float f) {
    uint u = __float_as_uint(f);
    u += 0x7FFF + ((u >> 16) & 1);   // round-to-nearest-even
    return (ushort)(u >> 16);
}
__device__ __forceinline__ uint packb(float lo, float hi) {
    return ((uint)f2b(hi) << 16) | (uint)f2b(lo);
}
__device__ __forceinline__ int xcd_chunk(int bid) {
    return (bid & 7) * (NCHUNK / 8) + (bid >> 3);
}

// ================= setup mega-kernel: hist | convert_x | convert_w | zero =================
#define B_CX 6250   // M*32/256
#define B_CW 192    // 3*16384/256
#define B_Z  8      // 2048 floats of statsrep
__global__ __launch_bounds__(256) void setup_kernel(const int* __restrict__ dst, int nE, int chunk,
                                                    int* __restrict__ histT,
                                                    const float4* __restrict__ x4,
                                                    ushort4* __restrict__ xb,
                                                    const float* __restrict__ w11,
                                                    const float* __restrict__ w12,
                                                    const float* __restrict__ w21,
                                                    ushort* __restrict__ o11,
                                                    ushort* __restrict__ o12,
                                                    ushort* __restrict__ o21,
                                                    float* __restrict__ statsrep) {
    __shared__ int h[NBUCK];
    const int b = blockIdx.x;
    const int tid = threadIdx.x;
    if (b < NCHUNK) {
        for (int i = tid; i < NBUCK; i += 256) h[i] = 0;
        __syncthreads();
        const int c = xcd_chunk(b);
        const int lo = c * chunk, hi = min(lo + chunk, nE);
        for (int i = lo + tid; i < hi; i += 256) atomicAdd(&h[dst[i] >> 7], 1);
        __syncthreads();
        for (int k = tid; k < NBUCK; k += 256) histT[k * NCHUNK + c] = h[k];
    } else if (b < NCHUNK + B_CX) {
        int i = (b - NCHUNK) * 256 + tid;
        float4 v = x4[i];
        ushort4 o;
        o.x = f2b(v.x); o.y = f2b(v.y); o.z = f2b(v.z); o.w = f2b(v.w);
        xb[i] = o;
    } else if (b < NCHUNK + B_CX + B_CW) {
        int id = (b - NCHUNK - B_CX) * 256 + tid;     // 0..49151
        int m = id >> 14;
        int within = id & 16383;
        int k = within >> 7, n = within & 127;
        const float* W = (m == 0) ? w11 : (m == 1) ? w12 : w21;
        ushort* O = (m == 0) ? o11 : (m == 1) ? o12 : o21;
        O[n * 128 + k] = f2b(W[within]);
    } else {
        int i = (b - NCHUNK - B_CX - B_CW) * 256 + tid;
        if (i < 2048) statsrep[i] = 0.f;
    }
}

// ================= radix: per-bucket totals =================
__global__ __launch_bounds__(256) void tot_kernel(const int* __restrict__ histT,
                                                  int* __restrict__ tot) {
    __shared__ int s[256];
    int acc = 0;
    for (int i = threadIdx.x; i < NCHUNK; i += 256) acc += histT[blockIdx.x * NCHUNK + i];
    s[threadIdx.x] = acc;
    __syncthreads();
    for (int d = 128; d > 0; d >>= 1) {
        if (threadIdx.x < d) s[threadIdx.x] += s[threadIdx.x + d];
        __syncthreads();
    }
    if (threadIdx.x == 0) tot[blockIdx.x] = s[0];
}

// ================= radix: per-bucket base + per-chunk exclusive offsets =================
__global__ __launch_bounds__(512) void base_scan_kernel(const int* __restrict__ tot,
                                                        const int* __restrict__ histT,
                                                        int* __restrict__ base_bc,
                                                        int* __restrict__ bucketbase,
                                                        int* __restrict__ rowptr, int nE) {
    __shared__ int s[512];
    const int b = blockIdx.x;
    const int t = threadIdx.x;
    // bucket base = sum of tot[0..b)
    int acc = 0;
    for (int i = t; i < b; i += 512) acc += tot[i];
    s[t] = acc;
    __syncthreads();
    for (int d = 256; d > 0; d >>= 1) {
        if (t < d) s[t] += s[t + d];
        __syncthreads();
    }
    const int bbase = s[0];
    __syncthreads();
    // inclusive scan of this bucket's chunk counts (NCHUNK == 512 threads)
    int v = (t < NCHUNK) ? histT[b * NCHUNK + t] : 0;
    s[t] = v;
    __syncthreads();
    for (int d = 1; d < 512; d <<= 1) {
        int u = (t >= d) ? s[t - d] : 0;
        __syncthreads();
        s[t] += u;
        __syncthreads();
    }
    if (t < NCHUNK) base_bc[b * NCHUNK + t] = bbase + s[t] - v;  // exclusive
    if (t == 0) {
        bucketbase[b] = bbase;
        if (b == NBUCK - 1) bucketbase[NBUCK] = bbase + tot[b];
        if (b == 0) rowptr[N_NODES] = nE;
    }
}

// ================= radix pass 2: placement =================
__global__ __launch_bounds__(256) void place_kernel(const int* __restrict__ src,
                                                    const int* __restrict__ dst, int nE,
                                                    int chunk,
                                                    const int* __restrict__ base_bc,
                                                    uint* __restrict__ bdata) {
    __shared__ int off[NBUCK];
    const int c = xcd_chunk(blockIdx.x);
    for (int i = threadIdx.x; i < NBUCK; i += 256) off[i] = base_bc[i * NCHUNK + c];
    __syncthreads();
    const int lo = c * chunk, hi = min(lo + chunk, nE);
    for (int i = lo + threadIdx.x; i < hi; i += 256) {
        int s = src[i], d = dst[i];
        int pos = atomicAdd(&off[d >> 7], 1);
        bdata[pos] = ((uint)(d & 127) << 16) | (uint)s;
    }
}

// ================= per-bucket LDS counting sort -> rowptr + perm =================
__global__ __launch_bounds__(256) void csr_build_kernel(const int* __restrict__ bucketbase,
                                                        const uint* __restrict__ bdata,
                                                        int* __restrict__ rowptr,
                                                        ushort* __restrict__ perm, int M) {
    __shared__ uint ent[ENTCAP];
    __shared__ int hist[128];
    __shared__ int scn[128];
    __shared__ int cur[128];
    const int b = blockIdx.x;
    const int tid = threadIdx.x;
    const int bb = bucketbase[b];
    const int nb = min(bucketbase[b + 1] - bb, ENTCAP);
    if (tid < 128) hist[tid] = 0;
    for (int i = tid; i < nb; i += 256) ent[i] = bdata[bb + i];
    __syncthreads();
    for (int i = tid; i < nb; i += 256) atomicAdd(&hist[ent[i] >> 16], 1);
    __syncthreads();
    if (tid < 128) scn[tid] = hist[tid];
    __syncthreads();
    for (int d = 1; d < 128; d <<= 1) {
        int v = 0;
        if (tid < 128 && tid >= d) v = scn[tid - d];
        __syncthreads();
        if (tid < 128) scn[tid] += v;
        __syncthreads();
    }
    if (tid < 128) {
        int ex = scn[tid] - hist[tid];
        cur[tid] = ex;
        int node = b * 128 + tid;
        if (node < M) rowptr[node] = bb + ex;
    }
    __syncthreads();
    for (int i = tid; i < nb; i += 256) {
        uint e = ent[i];
        int lp = atomicAdd(&cur[e >> 16], 1);
        perm[bb + lp] = (ushort)(e & 0xffffu);
    }
}

// ================= gather (16 lanes/edge, 4-deep), optional fused BN finalize+apply ======
#define ACC4(v) { acc[0] += blo(v.x); acc[1] += bhi(v.x); \
                  acc[2] += blo(v.y); acc[3] += bhi(v.y); \
                  acc[4] += blo(v.z); acc[5] += bhi(v.z); \
                  acc[6] += blo(v.w); acc[7] += bhi(v.w); }

template<bool BN>
__global__ __launch_bounds__(256) void gather_kernel(const uint4* __restrict__ xb,
                                                     const int* __restrict__ rowptr,
                                                     const ushort* __restrict__ perm,
                                                     const float* __restrict__ statsrep,
                                                     const float* __restrict__ gma,
                                                     const float* __restrict__ bta,
                                                     float invM,
                                                     uint4* __restrict__ out, int M) {
    __shared__ float scs[128], shs[128];
    if (BN) {
        if (threadIdx.x < 128) {
            int c = threadIdx.x;
            float s = 0.f, q = 0.f;
            #pragma unroll
            for (int rep = 0; rep < 8; ++rep) {
                s += statsrep[rep * 256 + c];
                q += statsrep[rep * 256 + 128 + c];
            }
            float mean = s * invM;
            float var = q * invM - mean * mean;
            float sc = rsqrtf(var + BN_EPS) * gma[c];
            scs[c] = sc;
            shs[c] = bta[c] - mean * sc;
        }
        __syncthreads();
    }
    const int node = blockIdx.x * 4 + (threadIdx.x >> 6);
    if (node >= M) return;
    const int lane = threadIdx.x & 63;
    const int g4 = lane >> 4;       // edge slot 0..3
    const int r = lane & 15;        // 16B chunk (features r*8 .. r*8+7)
    float acc[8];
    if (g4 == 0) {
        uint4 v = xb[node * 16 + r];
        acc[0] = blo(v.x); acc[1] = bhi(v.x);
        acc[2] = blo(v.y); acc[3] = bhi(v.y);
        acc[4] = blo(v.z); acc[5] = bhi(v.z);
        acc[6] = blo(v.w); acc[7] = bhi(v.w);
    } else {
        #pragma unroll
        for (int k = 0; k < 8; ++k) acc[k] = 0.f;
    }
    const int beg = rowptr[node], end = rowptr[node + 1];
    int e = beg + g4;
    while (e + 12 < end) {
        int s0 = perm[e], s1 = perm[e + 4], s2 = perm[e + 8], s3 = perm[e + 12];
        uint4 v0 = xb[s0 * 16 + r];
        uint4 v1 = xb[s1 * 16 + r];
        uint4 v2 = xb[s2 * 16 + r];
        uint4 v3 = xb[s3 * 16 + r];
        ACC4(v0); ACC4(v1); ACC4(v2); ACC4(v3);
        e += 16;
    }
    while (e + 4 < end) {
        int s0 = perm[e], s1 = perm[e + 4];
        uint4 v0 = xb[s0 * 16 + r];
        uint4 v1 = xb[s1 * 16 + r];
        ACC4(v0); ACC4(v1);
        e += 8;
    }
    if (e < end) {
        uint4 v0 = xb[(int)perm[e] * 16 + r];
        ACC4(v0);
    }
    #pragma unroll
    for (int k = 0; k < 8; ++k) {
        acc[k] += __shfl_xor(acc[k], 16);
        acc[k] += __shfl_xor(acc[k], 32);
    }
    if (g4 == 0) {
        if (BN) {
            const int f0 = r * 8;
            const float deg1 = (float)(end - beg + 1);
            #pragma unroll
            for (int k = 0; k < 8; ++k)
                acc[k] = acc[k] * scs[f0 + k] + deg1 * shs[f0 + k];
        }
        uint4 o;
        o.x = packb(acc[0], acc[1]);
        o.y = packb(acc[2], acc[3]);
        o.z = packb(acc[4], acc[5]);
        o.w = packb(acc[6], acc[7]);
        out[node * 16 + r] = o;
    }
}

// ================= fused layer-1: relu(A@W11+b11)@W12+b12 -> relu -> C + stats ============
// per-wave private bf16 LDS strip (no __syncthreads, 17.9KB), vector LDS reads.
__global__ __launch_bounds__(256) void mmL1_fused_kernel(const ushort* __restrict__ A,
                                                         const ushort* __restrict__ Wt1,
                                                         const float* __restrict__ b1,
                                                         const ushort* __restrict__ Wt2,
                                                         const float* __restrict__ b2,
                                                         ushort* __restrict__ C,
                                                         float* __restrict__ statsrep, int M) {
    __shared__ ushort T[4][16][140];   // per-wave [16 rows][128 cols + pad]
    const int wid = threadIdx.x >> 6;
    const int lane = threadIdx.x & 63;
    const int row0 = blockIdx.x * 64 + wid * 16;
    const int r = lane & 15;
    const int kg = lane >> 4;

    const int arow = min(row0 + r, M - 1);
    const ushort* Arow = A + (size_t)arow * 128 + kg * 8;
    short8 a[4];
    #pragma unroll
    for (int kb = 0; kb < 4; ++kb)
        a[kb] = *(const short8*)(Arow + kb * 32);

    // GEMM1 -> per-wave LDS strip (bf16, post-relu). Write mirrors the verified C-store
    // pattern: value (c,j) belongs at [row = kg*4+j][col = c*16+r].
    #pragma unroll
    for (int c = 0; c < 8; ++c) {
        f32x4 acc = {0.f, 0.f, 0.f, 0.f};
        const ushort* Wcol = Wt1 + (size_t)(c * 16 + r) * 128 + kg * 8;
        #pragma unroll
        for (int kb = 0; kb < 4; ++kb) {
            short8 bb = *(const short8*)(Wcol + kb * 32);
            acc = __builtin_amdgcn_mfma_f32_16x16x32_bf16(a[kb], bb, acc, 0, 0, 0);
        }
        const float bias = b1[c * 16 + r];
        #pragma unroll
        for (int j = 0; j < 4; ++j)
            T[wid][kg * 4 + j][c * 16 + r] = f2b(fmaxf(acc[j] + bias, 0.f));
    }
    // Same-wave LDS ops are processed in order: no barrier needed (private strip).

    // A2 fragments: read mirrors the verified A-load pattern: row r, cols kb*32+kg*8..+7.
    short8 a2[4];
    #pragma unroll
    for (int kb = 0; kb < 4; ++kb) {
        short4v lo = *(const short4v*)&T[wid][r][kb * 32 + kg * 8];
        short4v hi = *(const short4v*)&T[wid][r][kb * 32 + kg * 8 + 4];
        a2[kb][0] = lo[0]; a2[kb][1] = lo[1]; a2[kb][2] = lo[2]; a2[kb][3] = lo[3];
        a2[kb][4] = hi[0]; a2[kb][5] = hi[1]; a2[kb][6] = hi[2]; a2[kb][7] = hi[3];
    }

    // GEMM2 + epilogue (store + BN1 stats)
    float* sr = statsrep + (blockIdx.x & 7) * 256;
    #pragma unroll
    for (int c = 0; c < 8; ++c) {
        f32x4 acc = {0.f, 0.f, 0.f, 0.f};
        const ushort* Wcol = Wt2 + (size_t)(c * 16 + r) * 128 + kg * 8;
        #pragma unroll
        for (int kb = 0; kb < 4; ++kb) {
            short8 bb = *(const short8*)(Wcol + kb * 32);
            acc = __builtin_amdgcn_mfma_f32_16x16x32_bf16(a2[kb], bb, acc, 0, 0, 0);
        }
        const float bias = b2[c * 16 + r];
        float s = 0.f, q = 0.f;
        #pragma unroll
        for (int j = 0; j < 4; ++j) {
            int orow = row0 + kg * 4 + j;
            float v = fmaxf(acc[j] + bias, 0.f);
            if (orow < M) C[(size_t)orow * 128 + c * 16 + r] = f2b(v);
            else v = 0.f;
            s += v; q += v * v;
        }
        s += __shfl_xor(s, 16); s += __shfl_xor(s, 32);
        q += __shfl_xor(q, 16); q += __shfl_xor(q, 32);
        if (kg == 0) {
            atomicAdd(&sr[c * 16 + r], s);
            atomicAdd(&sr[128 + c * 16 + r], q);
        }
    }
}

// ================= fused layer-2 tail: relu(A@W21+b21)@W22+b22 -> relu -> h2 + pblk ======
__global__ __launch_bounds__(256) void mm2_fused_kernel(const ushort* __restrict__ A,
                                                        const ushort* __restrict__ Wt,
                                                        const float* __restrict__ b1,
                                                        const float* __restrict__ W22,
                                                        const float* __restrict__ b22,
                                                        float* __restrict__ h2,
                                                        float4* __restrict__ pblk, int M) {
    __shared__ float bred[4][4];
    const int wid = threadIdx.x >> 6;
    const int lane = threadIdx.x & 63;
    const int row0 = blockIdx.x * 64 + wid * 16;
    const int r = lane & 15;
    const int kg = lane >> 4;

    const int arow = min(row0 + r, M - 1);
    const ushort* Arow = A + (size_t)arow * 128 + kg * 8;
    short8 a[4];
    #pragma unroll
    for (int kb = 0; kb < 4; ++kb)
        a[kb] = *(const short8*)(Arow + kb * 32);

    float w2a[8], w2b[8];
    #pragma unroll
    for (int c = 0; c < 8; ++c) {
        w2a[c] = W22[(c * 16 + r) * 2 + 0];
        w2b[c] = W22[(c * 16 + r) * 2 + 1];
    }

    float s0[4] = {0.f, 0.f, 0.f, 0.f};
    float s1[4] = {0.f, 0.f, 0.f, 0.f};
    #pragma unroll
    for (int c = 0; c < 8; ++c) {
        f32x4 acc = {0.f, 0.f, 0.f, 0.f};
        const ushort* Wcol = Wt + (size_t)(c * 16 + r) * 128 + kg * 8;
        #pragma unroll
        for (int kb = 0; kb < 4; ++kb) {
            short8 bb = *(const short8*)(Wcol + kb * 32);
            acc = __builtin_amdgcn_mfma_f32_16x16x32_bf16(a[kb], bb, acc, 0, 0, 0);
        }
        float bias = b1[c * 16 + r];
        #pragma unroll
        for (int j = 0; j < 4; ++j) {
            int orow = row0 + kg * 4 + j;
            float v = fmaxf(acc[j] + bias, 0.f);
            if (orow >= M) v = 0.f;
            s0[j] += v * w2a[c];
            s1[j] += v * w2b[c];
        }
    }
    #pragma unroll
    for (int j = 0; j < 4; ++j) {
        #pragma unroll
        for (int d = 1; d < 16; d <<= 1) {
            s0[j] += __shfl_xor(s0[j], d);
            s1[j] += __shfl_xor(s1[j], d);
        }
    }
    float bs[4] = {0.f, 0.f, 0.f, 0.f};
    if (r == 0) {
        const float bb0 = b22[0], bb1 = b22[1];
        #pragma unroll
        for (int j = 0; j < 4; ++j) {
            int orow = row0 + kg * 4 + j;
            if (orow < M) {
                float o0 = fmaxf(s0[j] + bb0, 0.f);
                float o1 = fmaxf(s1[j] + bb1, 0.f);
                h2[(size_t)orow * 2 + 0] = o0;
                h2[(size_t)orow * 2 + 1] = o1;
                bs[0] += o0; bs[1] += o1; bs[2] += o0 * o0; bs[3] += o1 * o1;
            }
        }
    }
    #pragma unroll
    for (int k = 0; k < 4; ++k) {
        bs[k] += __shfl_xor(bs[k], 16);
        bs[k] += __shfl_xor(bs[k], 32);
    }
    if (lane == 0) {
        #pragma unroll
        for (int k = 0; k < 4; ++k) bred[wid][k] = bs[k];
    }
    __syncthreads();
    if (threadIdx.x == 0)
        pblk[blockIdx.x] = make_float4(bred[0][0] + bred[1][0] + bred[2][0] + bred[3][0],
                                       bred[0][1] + bred[1][1] + bred[2][1] + bred[3][1],
                                       bred[0][2] + bred[1][2] + bred[2][2] + bred[3][2],
                                       bred[0][3] + bred[1][3] + bred[2][3] + bred[3][3]);
}

// ================= final: reduce pblk -> BN2 scale/shift -> apply, f32 out =================
__global__ __launch_bounds__(256) void bn_apply2_kernel(const float* __restrict__ h,
                                                        const float4* __restrict__ pblk, int nblk,
                                                        const float* __restrict__ gma,
                                                        const float* __restrict__ bta,
                                                        float* __restrict__ y, int n4, float invM) {
    __shared__ float4 red[256];
    const int tid = threadIdx.x;
    float4 s = make_float4(0.f, 0.f, 0.f, 0.f);
    for (int b = tid; b < nblk; b += 256) {
        float4 t = pblk[b];
        s.x += t.x; s.y += t.y; s.z += t.z; s.w += t.w;
    }
    red[tid] = s;
    __syncthreads();
    for (int d = 128; d > 0; d >>= 1) {
        if (tid < d) {
            red[tid].x += red[tid + d].x;
            red[tid].y += red[tid + d].y;
            red[tid].z += red[tid + d].z;
            red[tid].w += red[tid + d].w;
        }
        __syncthreads();
    }
    const float4 tot = red[0];
    const float m0 = tot.x * invM, m1 = tot.y * invM;
    const float v0 = tot.z * invM - m0 * m0, v1 = tot.w * invM - m1 * m1;
    const float sc0 = rsqrtf(v0 + BN_EPS) * gma[0], sc1 = rsqrtf(v1 + BN_EPS) * gma[1];
    const float sh0 = bta[0] - m0 * sc0, sh1 = bta[1] - m1 * sc1;
    int gid = blockIdx.x * 256 + tid;
    if (gid >= n4) return;
    float4 v = ((const float4*)h)[gid];
    float4 o;
    o.x = v.x * sc0 + sh0;
    o.y = v.y * sc1 + sh1;
    o.z = v.z * sc0 + sh0;
    o.w = v.w * sc1 + sh1;
    ((float4*)y)[gid] = o;
}

extern "C" void kernel_launch(void* const* d_in, const int* in_sizes, int n_in,
                              void* d_out, int out_size, void* d_ws, size_t ws_size,
                              hipStream_t stream) {
    const float* x   = (const float*)d_in[0];
    const int*   ei  = (const int*)d_in[1];
    const float* w11 = (const float*)d_in[2];
    const float* b11 = (const float*)d_in[3];
    const float* w12 = (const float*)d_in[4];
    const float* b12 = (const float*)d_in[5];
    const float* g1  = (const float*)d_in[6];
    const float* be1 = (const float*)d_in[7];
    const float* w21 = (const float*)d_in[8];
    const float* b21 = (const float*)d_in[9];
    const float* w22 = (const float*)d_in[10];
    const float* b22 = (const float*)d_in[11];
    const float* g2  = (const float*)d_in[12];
    const float* be2 = (const float*)d_in[13];

    const int M  = N_NODES;
    const int nE = in_sizes[1] / 2;
    const int* src = ei;
    const int* dst = ei + nE;
    const int chunk = (nE + NCHUNK - 1) / NCHUNK;
    const int nblk = (M + 63) / 64;

    const size_t RB = (size_t)50048 * 128 * 2;      // padded bf16 feature buffer bytes
    char* p = (char*)d_ws;
    ushort* xb   = (ushort*)p;  p += RB;
    ushort* gbuf = (ushort*)p;  p += RB;
    ushort* hbuf = (ushort*)p;  p += RB;
    float*  h2   = (float*)p;   p += 400128;        // 50000*2 f32
    ushort* wt11 = (ushort*)p;  p += 32768;
    ushort* wt12 = (ushort*)p;  p += 32768;
    ushort* wt21 = (ushort*)p;  p += 32768;
    float* statsrep = (float*)p; p += 2048 * 4;     // 8 x (sum[128], sumsq[128])
    float4* pblk = (float4*)p;  p += (size_t)nblk * 16 + 64;
    int*  histT  = (int*)p;     p += (size_t)NBUCK * NCHUNK * 4;
    int*  base_bc= (int*)p;     p += (size_t)NBUCK * NCHUNK * 4;
    int*  tot    = (int*)p;     p += 512 * 4;
    int*  bktbase= (int*)p;     p += 512 * 4;
    int*  rowptr = (int*)p;     p += (size_t)(M + 8) * 4;
    ushort* perm = (ushort*)p;  p += (size_t)nE * 2 + 64;
    uint*  bdata = (uint*)p;

    const float invM = 1.0f / (float)M;

    // ---- setup: hist + convert_x + convert_w + zero (one dispatch) ----
    setup_kernel<<<NCHUNK + B_CX + B_CW + B_Z, 256, 0, stream>>>(
        dst, nE, chunk, histT, (const float4*)x, (ushort4*)xb,
        w11, w12, w21, wt11, wt12, wt21, statsrep);
    // ---- CSR build ----
    tot_kernel<<<NBUCK, 256, 0, stream>>>(histT, tot);
    base_scan_kernel<<<NBUCK, 512, 0, stream>>>(tot, histT, base_bc, bktbase, rowptr, nE);
    place_kernel<<<NCHUNK, 256, 0, stream>>>(src, dst, nE, chunk, base_bc, bdata);
    csr_build_kernel<<<NBUCK, 256, 0, stream>>>(bktbase, bdata, rowptr, perm, M);

    // ---- layer 1 (both GEMMs + BN1 stats fused, per-wave LDS transpose) ----
    gather_kernel<false><<<(M + 3) / 4, 256, 0, stream>>>((const uint4*)xb, rowptr, perm,
                                                          nullptr, nullptr, nullptr, 0.f,
                                                          (uint4*)gbuf, M);
    mmL1_fused_kernel<<<nblk, 256, 0, stream>>>(gbuf, wt11, b11, wt12, b12, hbuf, statsrep, M);

    // ---- layer 2 (BN1 finalize+fold fused into gather; 128->2 projection fused into GEMM) ----
    gather_kernel<true><<<(M + 3) / 4, 256, 0, stream>>>((const uint4*)hbuf, rowptr, perm,
                                                         statsrep, g1, be1, invM,
                                                         (uint4*)gbuf, M);
    mm2_fused_kernel<<<nblk, 256, 0, stream>>>(gbuf, wt21, b21, w22, b22, h2, pblk, M);
    bn_apply2_kernel<<<(M / 2 + 255) / 256, 256, 0, stream>>>(h2, pblk, nblk, g2, be2,
                                                              (float*)d_out, M / 2, invM);
}